// Round 5
// baseline (6079.372 us; speedup 1.0000x reference)
//
#include <hip/hip_runtime.h>

typedef __bf16 bf16x8 __attribute__((ext_vector_type(8)));
typedef float f32x4 __attribute__((ext_vector_type(4)));
typedef unsigned short u16;
typedef unsigned int u32;

typedef __attribute__((address_space(3))) u16 lds_u16;
typedef __attribute__((address_space(1))) const u16 glb_u16;

#define NJC 4

__device__ inline float bf2f(u16 u) { union { u32 i; float f; } x; x.i = (u32)u << 16; return x.f; }
__device__ inline u16 f2bf(float f) {
  union { float f; u32 i; } u; u.f = f;
  u32 r = u.i + 0x7fffu + ((u.i >> 16) & 1u);
  return (u16)(r >> 16);
}

__device__ inline float blk_sum256(float v, float* red) {
#pragma unroll
  for (int o = 32; o > 0; o >>= 1) v += __shfl_xor(v, o);
  __syncthreads();
  if ((threadIdx.x & 63) == 0) red[threadIdx.x >> 6] = v;
  __syncthreads();
  return red[0] + red[1] + red[2] + red[3];
}

// ============ kv-projection GEMM: 256x256 tile, 8 waves, 2 blocks/CU =================
// Ring-2 (64 KiB LDS) so TWO blocks co-reside per CU: one block's MFMA covers the
// other's barrier/vmcnt stalls (counters showed 42% idle at 1 block/CU regardless of
// schedule). Ledger: stage(t+2) issued only after the barrier that retires all reads
// of slot t&1; vmcnt(4) keeps exactly one subtile in flight.
__global__ __launch_bounds__(512, 4) void gemm_kv(const u16* __restrict__ A,
                                                  const u16* __restrict__ BT,
                                                  u16* __restrict__ C,
                                                  const float* __restrict__ bias) {
  extern __shared__ __align__(16) u16 lds[];  // [2 slots][2 (A,B)][8192 elems] = 64 KiB
  const int tid = threadIdx.x, l = tid & 63, w = tid >> 6;
  const int wr = w >> 2, wc = w & 3;  // 2 x 4 wave grid; per-wave out 128x64
  int bid = blockIdx.x;
  int swz = (bid & 7) * 128 + (bid >> 3);  // XCD chunking (bijective, 1024%8==0)
  int by = swz >> 3, bx = swz & 7;
  const long m0 = (long)by * 256;
  const int n0 = bx * 256;

  long srcA[2], srcB[2];
#pragma unroll
  for (int s = 0; s < 2; s++) {
    int g = s * 512 + tid;
    int p = g >> 3, j = g & 7, jp = j ^ (p & 7);
    int row = (p << 1) | (jp >> 2), cc = jp & 3;
    srcA[s] = (m0 + row) * 1024 + cc * 8;
    srcB[s] = ((long)(n0 + row)) * 1024 + cc * 8;
  }
  const int ldsoff[2] = { (w * 64) * 8, (512 + w * 64) * 8 };

  const int rA = l & 15, cch = l >> 4;
  const int R0a = wr * 128 + rA;
  const int aoff = (R0a >> 1) * 64 + (((((R0a & 1) << 2) | cch) ^ ((R0a >> 1) & 7)) << 3);
  const int R0b = wc * 64 + rA;
  const int boff = (R0b >> 1) * 64 + (((((R0b & 1) << 2) | cch) ^ ((R0b >> 1) & 7)) << 3);

  f32x4 acc[8][4] = {};

  auto stage = [&](int t, int ab) {
    u16* dst = lds + (((t & 1) * 2 + ab) << 13);
    const u16* src = ab == 0 ? A : BT;
    const long* so = ab == 0 ? srcA : srcB;
    int kt = t * 32;
#pragma unroll
    for (int s = 0; s < 2; s++)
      __builtin_amdgcn_global_load_lds((glb_u16*)(src + so[s] + kt),
                                       (lds_u16*)(dst + ldsoff[s]), 16, 0, 0);
  };

  // prologue: subtiles 0 and 1 (8 loads); wait for subtile 0 (leave 1 in flight)
  stage(0, 0); stage(0, 1); stage(1, 0); stage(1, 1);
  asm volatile("s_waitcnt vmcnt(4)" ::: "memory");
  __builtin_amdgcn_s_barrier();

  for (int t = 0; t < 32; ++t) {
    const u16* Ab = lds + (((t & 1) * 2 + 0) << 13);
    const u16* Bb = Ab + 8192;
    bf16x8 af[8], bf[4];
#pragma unroll
    for (int mf = 0; mf < 8; mf++) af[mf] = *(const bf16x8*)(Ab + aoff + mf * 512);
#pragma unroll
    for (int nf = 0; nf < 4; nf++) bf[nf] = *(const bf16x8*)(Bb + boff + nf * 512);
    asm volatile("s_waitcnt lgkmcnt(0)" ::: "memory");
    __builtin_amdgcn_sched_barrier(0);
    __builtin_amdgcn_s_barrier();          // all waves done reading slot t&1
    if (t + 2 < 32) { stage(t + 2, 0); stage(t + 2, 1); }  // overwrite slot safely
    __builtin_amdgcn_s_setprio(1);
#pragma unroll
    for (int mf = 0; mf < 8; mf++)
#pragma unroll
      for (int nf = 0; nf < 4; nf++)
        acc[mf][nf] = __builtin_amdgcn_mfma_f32_16x16x32_bf16(af[mf], bf[nf], acc[mf][nf], 0, 0, 0);
    __builtin_amdgcn_s_setprio(0);
    if (t + 2 < 32)      asm volatile("s_waitcnt vmcnt(4)" ::: "memory");  // t+1 landed
    else if (t + 1 < 32) asm volatile("s_waitcnt vmcnt(0)" ::: "memory");
    __builtin_amdgcn_sched_barrier(0);
    __builtin_amdgcn_s_barrier();
  }

  const long batch_off = (m0 >> 12) * ((long)4164 * 2048);
  const int rb0 = (int)(m0 & 4095) + wr * 128 + ((l >> 4) << 2);
#pragma unroll
  for (int mf = 0; mf < 8; mf++) {
#pragma unroll
    for (int nf = 0; nf < 4; nf++) {
      int col = n0 + wc * 64 + nf * 16 + (l & 15);
      float bv = bias[col];
#pragma unroll
      for (int rr = 0; rr < 4; rr++) {
        int rloc = rb0 + mf * 16 + rr;
        C[batch_off + (long)rloc * 2048 + col] = f2bf(acc[mf][nf][rr] + bv);
      }
    }
  }
}

// ---------------- general GEMM (small shapes): C = alpha*A@BT^T (+bias) -------------
// Ring-2 double-buffered staging with raw s_barrier + counted vmcnt.
// MODE 0: f32 store; 1: bf16 store; 2: f32 += (single writer); 3: f32 atomicAdd
template <int MODE, bool BIAS>
__global__ __launch_bounds__(256) void gemm_nt(const u16* __restrict__ A,
                                               const u16* __restrict__ BT,
                                               void* __restrict__ C,
                                               const float* __restrict__ bias,
                                               int M, int N, int K, float alpha,
                                               int RB, long BS, int LDC, int KC) {
  __shared__ __align__(16) u16 As[2][128 * 64];
  __shared__ __align__(16) u16 Bs[2][128 * 64];
  int m0 = blockIdx.y * 128, n0 = blockIdx.x * 128;
  int tid = threadIdx.x;
  int l = tid & 63, w = tid >> 6;
  int wr = w >> 1, wc = w & 1;
  f32x4 acc[4][4] = {};

  const int srow = l >> 3;
  const int scol = (l & 7) * 8;
  const int Mc = M - 1;
  const int k0 = blockIdx.z * KC;
  const int k1 = (k0 + KC < K) ? k0 + KC : K;

  auto stage = [&](int kt, int pb) {
#pragma unroll
    for (int r = 0; r < 4; r++) {
      int rowg = (r * 4 + w) * 8;
      int arow = m0 + rowg + srow; if (arow > Mc) arow = Mc;
      int brow = n0 + rowg + srow;
      const u16* ag = A + (long)arow * K + kt + scol;
      const u16* bg = BT + (long)brow * K + kt + scol;
      __builtin_amdgcn_global_load_lds((glb_u16*)ag, (lds_u16*)(&As[pb][rowg * 64]), 16, 0, 0);
      __builtin_amdgcn_global_load_lds((glb_u16*)bg, (lds_u16*)(&Bs[pb][rowg * 64]), 16, 0, 0);
    }
  };

  stage(k0, 0);
  int it = 0;
  for (int kt = k0; kt < k1; kt += 64, ++it) {
    const int pb = it & 1;
    const bool more = (kt + 64) < k1;
    if (more) stage(kt + 64, pb ^ 1);
    if (more) asm volatile("s_waitcnt vmcnt(8)" ::: "memory");
    else      asm volatile("s_waitcnt vmcnt(0)" ::: "memory");
    __builtin_amdgcn_sched_barrier(0);
    __builtin_amdgcn_s_barrier();
    const u16* Ab = &As[pb][0];
    const u16* Bb = &Bs[pb][0];
#pragma unroll
    for (int kk = 0; kk < 2; kk++) {
      bf16x8 af[4], bfv[4];
#pragma unroll
      for (int mf = 0; mf < 4; mf++)
        af[mf] = *(const bf16x8*)(Ab + (wr * 64 + mf * 16 + (l & 15)) * 64 + kk * 32 + (l >> 4) * 8);
#pragma unroll
      for (int nf = 0; nf < 4; nf++)
        bfv[nf] = *(const bf16x8*)(Bb + (wc * 64 + nf * 16 + (l & 15)) * 64 + kk * 32 + (l >> 4) * 8);
#pragma unroll
      for (int mf = 0; mf < 4; mf++)
#pragma unroll
        for (int nf = 0; nf < 4; nf++)
          acc[mf][nf] = __builtin_amdgcn_mfma_f32_16x16x32_bf16(af[mf], bfv[nf], acc[mf][nf], 0, 0, 0);
    }
    __builtin_amdgcn_sched_barrier(0);
    __builtin_amdgcn_s_barrier();
  }

#pragma unroll
  for (int mf = 0; mf < 4; mf++) {
#pragma unroll
    for (int nf = 0; nf < 4; nf++) {
      int col = n0 + wc * 64 + nf * 16 + (l & 15);
      float bv = 0.f;
      if (BIAS) bv = bias[col];
#pragma unroll
      for (int rr = 0; rr < 4; rr++) {
        int row = m0 + wr * 64 + mf * 16 + (l >> 4) * 4 + rr;
        if (row < M) {
          float v = acc[mf][nf][rr] * alpha + bv;
          long off = (long)(row / RB) * BS + (long)(row % RB) * LDC + col;
          if (MODE == 0) ((float*)C)[off] = v;
          else if (MODE == 1) ((u16*)C)[off] = f2bf(v);
          else if (MODE == 2) ((float*)C)[off] += v;
          else atomicAdd(&((float*)C)[off], v);
        }
      }
    }
  }
}

// ---------------- fused q-proj + kvlat-proj (both read lnlat, M=544, K=1024) --------
__global__ __launch_bounds__(256) void gemm_two(const u16* __restrict__ A,
                                                const u16* __restrict__ BTq,
                                                const u16* __restrict__ BTkv,
                                                u16* __restrict__ Cq,
                                                u16* __restrict__ Ckv) {
  __shared__ __align__(16) u16 As[2][128 * 64];
  __shared__ __align__(16) u16 Bs[2][128 * 64];
  const int K = 1024, M = 544;
  int bxr = blockIdx.x;
  const u16* BT; u16* C; float alpha; int RB; long BS; int LDC; int n0;
  if (bxr < 8) { BT = BTq;  C = Cq;  alpha = 0.125f; RB = 544; BS = 0;                 LDC = 1024; n0 = bxr * 128; }
  else         { BT = BTkv; C = Ckv; alpha = 1.f;    RB = 68;  BS = (long)4164 * 2048; LDC = 2048; n0 = (bxr - 8) * 128; }
  int m0 = blockIdx.y * 128;
  int tid = threadIdx.x;
  int l = tid & 63, w = tid >> 6;
  int wr = w >> 1, wc = w & 1;
  f32x4 acc[4][4] = {};

  const int srow = l >> 3;
  const int scol = (l & 7) * 8;
  const int Mc = M - 1;

  auto stage = [&](int kt, int pb) {
#pragma unroll
    for (int r = 0; r < 4; r++) {
      int rowg = (r * 4 + w) * 8;
      int arow = m0 + rowg + srow; if (arow > Mc) arow = Mc;
      int brow = n0 + rowg + srow;
      const u16* ag = A + (long)arow * K + kt + scol;
      const u16* bg = BT + (long)brow * K + kt + scol;
      __builtin_amdgcn_global_load_lds((glb_u16*)ag, (lds_u16*)(&As[pb][rowg * 64]), 16, 0, 0);
      __builtin_amdgcn_global_load_lds((glb_u16*)bg, (lds_u16*)(&Bs[pb][rowg * 64]), 16, 0, 0);
    }
  };

  stage(0, 0);
  int it = 0;
  for (int kt = 0; kt < K; kt += 64, ++it) {
    const int pb = it & 1;
    const bool more = (kt + 64) < K;
    if (more) stage(kt + 64, pb ^ 1);
    if (more) asm volatile("s_waitcnt vmcnt(8)" ::: "memory");
    else      asm volatile("s_waitcnt vmcnt(0)" ::: "memory");
    __builtin_amdgcn_sched_barrier(0);
    __builtin_amdgcn_s_barrier();
    const u16* Ab = &As[pb][0];
    const u16* Bb = &Bs[pb][0];
#pragma unroll
    for (int kk = 0; kk < 2; kk++) {
      bf16x8 af[4], bfv[4];
#pragma unroll
      for (int mf = 0; mf < 4; mf++)
        af[mf] = *(const bf16x8*)(Ab + (wr * 64 + mf * 16 + (l & 15)) * 64 + kk * 32 + (l >> 4) * 8);
#pragma unroll
      for (int nf = 0; nf < 4; nf++)
        bfv[nf] = *(const bf16x8*)(Bb + (wc * 64 + nf * 16 + (l & 15)) * 64 + kk * 32 + (l >> 4) * 8);
#pragma unroll
      for (int mf = 0; mf < 4; mf++)
#pragma unroll
        for (int nf = 0; nf < 4; nf++)
          acc[mf][nf] = __builtin_amdgcn_mfma_f32_16x16x32_bf16(af[mf], bfv[nf], acc[mf][nf], 0, 0, 0);
    }
    __builtin_amdgcn_sched_barrier(0);
    __builtin_amdgcn_s_barrier();
  }

#pragma unroll
  for (int mf = 0; mf < 4; mf++) {
#pragma unroll
    for (int nf = 0; nf < 4; nf++) {
      int col = n0 + wc * 64 + nf * 16 + (l & 15);
#pragma unroll
      for (int rr = 0; rr < 4; rr++) {
        int row = m0 + wr * 64 + mf * 16 + (l >> 4) * 4 + rr;
        if (row < M) {
          float v = acc[mf][nf][rr] * alpha;
          long off = (long)(row / RB) * BS + (long)(row % RB) * LDC + col;
          C[off] = f2bf(v);
        }
      }
    }
  }
}

// ---------------- transpose + optional row-scale + f32->bf16 (batched over z) -------
__global__ __launch_bounds__(256) void k_transpose(const float* __restrict__ W,
                                                   const float* __restrict__ scale,
                                                   u16* __restrict__ WT, int K, int N,
                                                   long wls, long sls, long tls) {
  __shared__ float tile[32][33];
  int z = blockIdx.z;
  W += (long)z * wls; WT += (long)z * tls;
  if (scale) scale += (long)z * sls;
  int n0 = blockIdx.x * 32, k0 = blockIdx.y * 32;
  int x = threadIdx.x, y = threadIdx.y;
#pragma unroll
  for (int i = 0; i < 4; i++) tile[y + 8 * i][x] = W[(long)(k0 + y + 8 * i) * N + n0 + x];
  __syncthreads();
#pragma unroll
  for (int i = 0; i < 4; i++) {
    int k = k0 + x, n = n0 + y + 8 * i;
    float v = tile[x][y + 8 * i];
    if (scale) v *= scale[k];
    WT[(long)n * K + k] = f2bf(v);
  }
}

__global__ __launch_bounds__(256) void k_transpose2(const float* __restrict__ W,
                                                    const float* __restrict__ scale,
                                                    u16* __restrict__ WTs,
                                                    u16* __restrict__ WTp, int K, int N,
                                                    long wls, long sls, long tls) {
  __shared__ float tile[32][33];
  int z = blockIdx.z;
  W += (long)z * wls; scale += (long)z * sls;
  WTs += (long)z * tls; WTp += (long)z * tls;
  int n0 = blockIdx.x * 32, k0 = blockIdx.y * 32;
  int x = threadIdx.x, y = threadIdx.y;
#pragma unroll
  for (int i = 0; i < 4; i++) tile[y + 8 * i][x] = W[(long)(k0 + y + 8 * i) * N + n0 + x];
  __syncthreads();
#pragma unroll
  for (int i = 0; i < 4; i++) {
    int k = k0 + x, n = n0 + y + 8 * i;
    float v = tile[x][y + 8 * i];
    WTp[(long)n * K + k] = f2bf(v);
    WTs[(long)n * K + k] = f2bf(v * scale[k]);
  }
}

// ---------------- xp_hat = normalize(x + pos_emb) per row, bf16 ---------------------
__global__ __launch_bounds__(256) void k_xphat(const float* __restrict__ x,
                                               const float* __restrict__ pos,
                                               u16* __restrict__ xph) {
  __shared__ float red[4];
  long row = blockIdx.x;
  int n = blockIdx.x & 4095;
  const float* xr = x + row * 1024;
  const float* pr = pos + (long)n * 1024;
  float v[4]; float s = 0.f;
#pragma unroll
  for (int i = 0; i < 4; i++) { int c = threadIdx.x + i * 256; v[i] = xr[c] + pr[c]; s += v[i]; }
  float mean = blk_sum256(s, red) * (1.f / 1024.f);
  float s2 = 0.f;
#pragma unroll
  for (int i = 0; i < 4; i++) { float d = v[i] - mean; s2 += d * d; }
  float rs = rsqrtf(blk_sum256(s2, red) * (1.f / 1024.f) + 1e-5f);
#pragma unroll
  for (int i = 0; i < 4; i++) xph[row * 1024 + threadIdx.x + i * 256] = f2bf((v[i] - mean) * rs);
}

// ---------------- mp: column sums of x over n ---------------------------------------
__global__ __launch_bounds__(256) void k_mp(const float* __restrict__ x, float* __restrict__ macc) {
  int d = blockIdx.x * 256 + threadIdx.x;
  int nc = blockIdx.y, b = blockIdx.z;
  const float* xb = x + (long)b * 4096 * 1024;
  float s = 0.f;
  for (int n = nc * 256; n < nc * 256 + 256; n++) s += xb[(long)n * 1024 + d];
  atomicAdd(&macc[b * 1024 + d], s);
}

__global__ __launch_bounds__(256) void k_mphat(const float* __restrict__ macc,
                                               const float* __restrict__ g,
                                               float* __restrict__ mphat) {
  __shared__ float red[4];
  int b = blockIdx.x;
  float v[4]; float s = 0.f;
#pragma unroll
  for (int i = 0; i < 4; i++) { v[i] = macc[b * 1024 + threadIdx.x + i * 256] * (1.f / 4096.f); s += v[i]; }
  float mean = blk_sum256(s, red) * (1.f / 1024.f);
  float s2 = 0.f;
#pragma unroll
  for (int i = 0; i < 4; i++) { float d = v[i] - mean; s2 += d * d; }
  float rs = rsqrtf(blk_sum256(s2, red) * (1.f / 1024.f) + 1e-5f);
#pragma unroll
  for (int i = 0; i < 4; i++) {
    int c = threadIdx.x + i * 256;
    mphat[b * 1024 + c] = (v[i] - mean) * rs * g[c];
  }
}

__global__ __launch_bounds__(256) void k_mplat(const float* __restrict__ mphat,
                                               const float* __restrict__ w,
                                               const float* __restrict__ bias,
                                               float* __restrict__ lat) {
  int j = blockIdx.x * 256 + threadIdx.x;
  int b = blockIdx.y;
  const float* mh = mphat + b * 1024;
  float s = bias[j];
  for (int k = 0; k < 1024; k++) s += mh[k] * w[(long)k * 4096 + j];
  lat[(long)b * 69632 + (j >> 10) * 1024 + (j & 1023)] = s;
}

__global__ __launch_bounds__(256) void k_latfill(const float* __restrict__ latents,
                                                 float* __restrict__ lat) {
  int idx = blockIdx.x * 256 + threadIdx.x;
  int b = idx >> 16, rest = idx & 65535;
  lat[(long)b * 69632 + 4096 + rest] = latents[rest];
}

// ---------------- lnlat = LN(lat)*w+b  -> bf16 -------------------------------------
__global__ __launch_bounds__(256) void k_lnrow(const float* __restrict__ in,
                                               const float* __restrict__ w,
                                               const float* __restrict__ bb,
                                               u16* __restrict__ out) {
  __shared__ float red[4];
  long row = blockIdx.x;
  const float* xr = in + row * 1024;
  float v[4]; float s = 0.f;
#pragma unroll
  for (int i = 0; i < 4; i++) { v[i] = xr[threadIdx.x + i * 256]; s += v[i]; }
  float mean = blk_sum256(s, red) * (1.f / 1024.f);
  float s2 = 0.f;
#pragma unroll
  for (int i = 0; i < 4; i++) { float d = v[i] - mean; s2 += d * d; }
  float rs = rsqrtf(blk_sum256(s2, red) * (1.f / 1024.f) + 1e-5f);
#pragma unroll
  for (int i = 0; i < 4; i++) {
    int c = threadIdx.x + i * 256;
    out[row * 1024 + c] = f2bf((v[i] - mean) * rs * w[c] + bb[c]);
  }
}

// ---------------- bias fold (batched over z = layer) --------------------------------
__global__ __launch_bounds__(256) void k_bias1(const float* __restrict__ wkv,
                                               const float* __restrict__ lnxb,
                                               float* __restrict__ bxp,
                                               long wls, long bls, long pls) {
  int z = blockIdx.z;
  wkv += (long)z * wls; lnxb += (long)z * bls; bxp += (long)z * pls;
  int n = blockIdx.x * 256 + threadIdx.x;
  int kc = blockIdx.y;
  float s = 0.f;
  for (int k = kc * 64; k < kc * 64 + 64; k++) s += lnxb[k] * wkv[(long)k * 2048 + n];
  bxp[kc * 2048 + n] = s;
}
__global__ __launch_bounds__(256) void k_bias2(const float* __restrict__ bxp,
                                               float* __restrict__ bx,
                                               long pls, long xls) {
  int z = blockIdx.y;
  bxp += (long)z * pls; bx += (long)z * xls;
  int n = blockIdx.x * 256 + threadIdx.x;
  float s = 0.f;
#pragma unroll
  for (int kc = 0; kc < 16; kc++) s += bxp[kc * 2048 + n];
  bx[n] = s;
}

// ---------------- MFMA flash attention, T14 software-pipelined ----------------------
__global__ __launch_bounds__(256) void k_flash(const u16* __restrict__ q,
                                               const u16* __restrict__ kv,
                                               float* __restrict__ opart,
                                               float* __restrict__ lpart) {
  int c = blockIdx.x, h = blockIdx.y, b = blockIdx.z;
  int tid = threadIdx.x, l = tid & 63, w = tid >> 6;

  __shared__ __align__(16) char smem_raw[46080];
  u16 (*Vt)[64][40] = reinterpret_cast<u16(*)[64][40]>(smem_raw);
  u16 (*Pl)[80][40] = reinterpret_cast<u16(*)[80][40]>(smem_raw + 20480);
  float (*O_s)[64] = reinterpret_cast<float(*)[64]>(smem_raw);
  float* l_s = reinterpret_cast<float*>(smem_raw + 20480);

  const int JCH = 1041;
  const int jstart = c * JCH;
  const int jend = (c == NJC - 1) ? 4164 : jstart + JCH;
  const long kvbase = (long)b * 4164 * 2048;
  const u16* Kp = kv + kvbase + h * 64;
  const u16* Vp = kv + kvbase + 1024 + h * 64;

  bf16x8 qf[5][2];
#pragma unroll
  for (int it = 0; it < 5; it++) {
    int qi = it * 16 + (l & 15); if (qi > 67) qi = 67;
    const u16* qrow = q + ((long)(b * 68 + qi) * 1024 + h * 64 + (l >> 4) * 8);
    qf[it][0] = *(const bf16x8*)(qrow);
    qf[it][1] = *(const bf16x8*)(qrow + 32);
  }

  f32x4 Of[5][4] = {};
  float lac[5] = {0.f, 0.f, 0.f, 0.f, 0.f};

  auto loadV = [&](int j0, uint4 vv[4]) {
#pragma unroll
    for (int t = 0; t < 4; t++) {
      int vj = j0 + (l & 31);
      int vjc = vj < 4163 ? vj : 4163;
      int vd = (l >> 5) * 8 + t * 16;
      vv[t] = *(const uint4*)(Vp + (long)vjc * 2048 + vd);
    }
  };
  auto loadK = [&](int j0, bf16x8& a00, bf16x8& a01, bf16x8& a10, bf16x8& a11) {
    const u16* kr0 = Kp + (long)(j0 + (l & 15)) * 2048 + (l >> 4) * 8;
    a00 = *(const bf16x8*)(kr0);
    a01 = *(const bf16x8*)(kr0 + 32);
    const u16* kr1 = Kp + (long)(j0 + 16 + (l & 15)) * 2048 + (l >> 4) * 8;
    a10 = *(const bf16x8*)(kr1);
    a11 = *(const bf16x8*)(kr1 + 32);
  };

  const int jbeg = jstart + w * 32;
  uint4 vr[4];
  bf16x8 k0a, k0b, k1a, k1b;
  if (jbeg < jend) { loadV(jbeg, vr); loadK(jbeg, k0a, k0b, k1a, k1b); }

  for (int j0 = jbeg; j0 < jend; j0 += 4 * 32) {
#pragma unroll
    for (int t = 0; t < 4; t++) {
      int vd = (l >> 5) * 8 + t * 16;
      union { uint4 q4; u16 s[8]; } uu; uu.q4 = vr[t];
#pragma unroll
      for (int e = 0; e < 8; e++) Vt[w][vd + e][l & 31] = uu.s[e];
    }
    f32x4 sf[2][5];
#pragma unroll
    for (int it = 0; it < 5; it++) {
      f32x4 d0 = {};
      d0 = __builtin_amdgcn_mfma_f32_16x16x32_bf16(k0a, qf[it][0], d0, 0, 0, 0);
      d0 = __builtin_amdgcn_mfma_f32_16x16x32_bf16(k0b, qf[it][1], d0, 0, 0, 0);
      sf[0][it] = d0;
      f32x4 d1 = {};
      d1 = __builtin_amdgcn_mfma_f32_16x16x32_bf16(k1a, qf[it][0], d1, 0, 0, 0);
      d1 = __builtin_amdgcn_mfma_f32_16x16x32_bf16(k1b, qf[it][1], d1, 0, 0, 0);
      sf[1][it] = d1;
    }
    int jn = j0 + 4 * 32;
    bool more = jn < jend;
    uint4 vr2[4];
    bf16x8 n0a, n0b, n1a, n1b;
    if (more) { loadV(jn, vr2); loadK(jn, n0a, n0b, n1a, n1b); }
#pragma unroll
    for (int jt = 0; jt < 2; jt++) {
      int jb = j0 + jt * 16 + (l >> 4) * 4;
#pragma unroll
      for (int it = 0; it < 5; it++) {
        u16 pk[4];
#pragma unroll
        for (int r = 0; r < 4; r++) {
          float p = (jb + r < jend) ? __expf(sf[jt][it][r]) : 0.f;
          lac[it] += p;
          pk[r] = f2bf(p);
        }
        *(uint2*)(&Pl[w][it * 16 + (l & 15)][jt * 16 + (l >> 4) * 4]) = *(const uint2*)pk;
      }
    }
#pragma unroll
    for (int it = 0; it < 5; it++) {
      bf16x8 pa = *(const bf16x8*)(&Pl[w][it * 16 + (l & 15)][(l >> 4) * 8]);
#pragma unroll
      for (int dt = 0; dt < 4; dt++) {
        bf16x8 vb = *(const bf16x8*)(&Vt[w][dt * 16 + (l & 15)][(l >> 4) * 8]);
        Of[it][dt] = __builtin_amdgcn_mfma_f32_16x16x32_bf16(pa, vb, Of[it][dt], 0, 0, 0);
      }
    }
    if (more) {
      vr[0] = vr2[0]; vr[1] = vr2[1]; vr[2] = vr2[2]; vr[3] = vr2[3];
      k0a = n0a; k0b = n0b; k1a = n1a; k1b = n1b;
    }
  }

  __syncthreads();
  for (int u = tid; u < 80 * 64; u += 256) ((float*)O_s)[u] = 0.f;
  if (tid < 80) l_s[tid] = 0.f;
  __syncthreads();
#pragma unroll
  for (int it = 0; it < 5; it++) {
    float v = lac[it];
    v += __shfl_xor(v, 16);
    v += __shfl_xor(v, 32);
    if (l < 16) atomicAdd(&l_s[it * 16 + l], v);
#pragma unroll
    for (int dt = 0; dt < 4; dt++) {
#pragma unroll
      for (int r = 0; r < 4; r++) {
        int i = it * 16 + (l >> 4) * 4 + r;
        int d = dt * 16 + (l & 15);
        atomicAdd(&O_s[i][d], Of[it][dt][r]);
      }
    }
  }
  __syncthreads();
  long base = (long)((b * 16 + h) * NJC + c);
  for (int u = tid; u < 68 * 64; u += 256)
    opart[base * 68 * 64 + u] = O_s[u >> 6][u & 63];
  if (tid < 68) lpart[base * 68 + tid] = l_s[tid];
}

// ---------------- combine partials -> obf bf16; also zero o2 for the wo split-K ----
__global__ __launch_bounds__(256) void k_comb(const float* __restrict__ opart,
                                              const float* __restrict__ lpart,
                                              u16* __restrict__ obf,
                                              float* __restrict__ o2z) {
  int r = blockIdx.x;
  int b = r / 68, i = r % 68;
#pragma unroll
  for (int it = 0; it < 4; it++) {
    int col = threadIdx.x + it * 256;
    int h = col >> 6, d = col & 63;
    long bh = (long)(b * 16 + h) * NJC;
    float os = 0.f, ls = 0.f;
    for (int cc = 0; cc < NJC; cc++) {
      os += opart[(bh + cc) * 68 * 64 + (long)i * 64 + d];
      ls += lpart[(bh + cc) * 68 + i];
    }
    obf[(long)r * 1024 + col] = f2bf(os / ls);
    o2z[(long)r * 1024 + col] = 0.f;
  }
}

// ---------------- o-path: lat += LN(o2)*w+b ; latg = LN_g(lat_new)*g ----------------
__global__ __launch_bounds__(256) void k_attnln(const float* __restrict__ o2,
                                                float* __restrict__ lat,
                                                const float* __restrict__ w,
                                                const float* __restrict__ bb,
                                                const float* __restrict__ g,
                                                u16* __restrict__ latg) {
  __shared__ float red[4];
  long row = blockIdx.x;
  const float* xr = o2 + row * 1024;
  float* lr = lat + row * 1024;
  float v[4]; float s = 0.f;
#pragma unroll
  for (int i = 0; i < 4; i++) { v[i] = xr[threadIdx.x + i * 256]; s += v[i]; }
  float mean = blk_sum256(s, red) * (1.f / 1024.f);
  float s2 = 0.f;
#pragma unroll
  for (int i = 0; i < 4; i++) { float d = v[i] - mean; s2 += d * d; }
  float rs = rsqrtf(blk_sum256(s2, red) * (1.f / 1024.f) + 1e-5f);
  float lv[4]; float sl = 0.f;
#pragma unroll
  for (int i = 0; i < 4; i++) {
    int c = threadIdx.x + i * 256;
    float t = (v[i] - mean) * rs * w[c] + bb[c];
    lv[i] = lr[c] + t;
    lr[c] = lv[i];
    sl += lv[i];
  }
  float mean2 = blk_sum256(sl, red) * (1.f / 1024.f);
  float s22 = 0.f;
#pragma unroll
  for (int i = 0; i < 4; i++) { float d = lv[i] - mean2; s22 += d * d; }
  float rs2 = rsqrtf(blk_sum256(s22, red) * (1.f / 1024.f) + 1e-5f);
#pragma unroll
  for (int i = 0; i < 4; i++) {
    int c = threadIdx.x + i * 256;
    latg[row * 1024 + c] = f2bf((lv[i] - mean2) * rs2 * g[c]);
  }
}

// ---------------- FF mid: hg = LN_g(gelu(h))*g2 -------------------------------------
__global__ __launch_bounds__(256) void k_geluln(const float* __restrict__ hin,
                                                const float* __restrict__ g,
                                                u16* __restrict__ out) {
  __shared__ float red[4];
  long row = blockIdx.x;
  const float* xr = hin + row * 4096;
  float v[16]; float s = 0.f;
#pragma unroll
  for (int i = 0; i < 16; i++) {
    int c = threadIdx.x + i * 256;
    float u = xr[c];
    u = 0.5f * u * (1.f + erff(u * 0.70710678118f));
    v[i] = u; s += u;
  }
  float mean = blk_sum256(s, red) * (1.f / 4096.f);
  float s2 = 0.f;
#pragma unroll
  for (int i = 0; i < 16; i++) { float d = v[i] - mean; s2 += d * d; }
  float rs = rsqrtf(blk_sum256(s2, red) * (1.f / 4096.f) + 1e-5f);
#pragma unroll
  for (int i = 0; i < 16; i++) {
    int c = threadIdx.x + i * 256;
    out[row * 4096 + c] = f2bf((v[i] - mean) * rs * g[c]);
  }
}

extern "C" void kernel_launch(void* const* d_in, const int* in_sizes, int n_in,
                              void* d_out, int out_size, void* d_ws, size_t ws_size,
                              hipStream_t stream) {
  const float* x    = (const float*)d_in[0];
  const float* pos  = (const float*)d_in[1];
  const float* lats = (const float*)d_in[2];
  const float* mplng= (const float*)d_in[3];
  const float* mpw  = (const float*)d_in[4];
  const float* mpb  = (const float*)d_in[5];
  const float* lnxw = (const float*)d_in[6];
  const float* lnxb = (const float*)d_in[7];
  const float* lnlw = (const float*)d_in[8];
  const float* lnlb = (const float*)d_in[9];
  const float* wq   = (const float*)d_in[10];
  const float* wkv  = (const float*)d_in[11];
  const float* wo   = (const float*)d_in[12];
  const float* olnw = (const float*)d_in[13];
  const float* olnb = (const float*)d_in[14];
  const float* ffg1 = (const float*)d_in[15];
  const float* ffw1 = (const float*)d_in[16];
  const float* ffg2 = (const float*)d_in[17];
  const float* ffw2 = (const float*)d_in[18];

  char* ws = (char*)d_ws;
  size_t off = 0;
  auto take = [&](size_t n) -> char* {
    off = (off + 255) & ~(size_t)255;
    char* p = ws + off; off += n; return p;
  };
  float* mp_acc = (float*)take(8 * 1024 * 4);
  float* mp_hat = (float*)take(8 * 1024 * 4);
  u16*   xp_hat = (u16*)take((size_t)8 * 4096 * 1024 * 2);
  float* lat    = (float*)take((size_t)8 * 68 * 1024 * 4);
  u16*   lnlat  = (u16*)take((size_t)544 * 1024 * 2);
  u16*   qb     = (u16*)take((size_t)544 * 1024 * 2);
  u16*   kvb    = (u16*)take(((size_t)8 * 4164 + 64) * 2048 * 2);
  float* opart  = (float*)take((size_t)128 * NJC * 68 * 64 * 4);
  float* lpart  = (float*)take((size_t)128 * NJC * 68 * 4);
  u16*   obf    = (u16*)take((size_t)544 * 1024 * 2);
  float* o2     = (float*)take((size_t)544 * 1024 * 4);
  u16*   latg   = (u16*)take((size_t)544 * 1024 * 2);
  float* hbuf   = (float*)take((size_t)544 * 4096 * 4);
  u16*   hg     = (u16*)take((size_t)544 * 4096 * 2);

  // weight buffers: try 4-layer-resident (hoisted prep); fall back to per-layer slots
  size_t fixed_off = off;
  u16 *wqT, *wkvxT, *wkvlT, *woT, *ffw1T, *ffw2T;
  float *bx, *bxp;
  auto alloc_w = [&](size_t rep) {
    wqT   = (u16*)take(rep * (size_t)1024 * 1024 * 2);
    wkvxT = (u16*)take(rep * (size_t)2048 * 1024 * 2);
    wkvlT = (u16*)take(rep * (size_t)2048 * 1024 * 2);
    woT   = (u16*)take(rep * (size_t)1024 * 1024 * 2);
    ffw1T = (u16*)take(rep * (size_t)4096 * 1024 * 2);
    ffw2T = (u16*)take(rep * (size_t)4096 * 1024 * 2);
    bx    = (float*)take(rep * 2048 * 4);
    bxp   = (float*)take(rep * 16 * 2048 * 4);
  };
  alloc_w(4);
  bool hoist = off <= ws_size;
  if (!hoist) { off = fixed_off; alloc_w(1); }

  const long KV_BS = (long)4164 * 2048;

  // ---- precompute ----
  hipMemsetAsync(mp_acc, 0, 8 * 1024 * 4, stream);
  k_xphat<<<32768, 256, 0, stream>>>(x, pos, xp_hat);
  k_mp<<<dim3(4, 16, 8), 256, 0, stream>>>(x, mp_acc);
  k_mphat<<<8, 256, 0, stream>>>(mp_acc, mplng, mp_hat);
  k_mplat<<<dim3(16, 8), 256, 0, stream>>>(mp_hat, mpw, mpb, lat);
  k_latfill<<<2048, 256, 0, stream>>>(lats, lat);

  if (hoist) {
    k_transpose<<<dim3(32, 32, 4), dim3(32, 8), 0, stream>>>(
        wq, nullptr, wqT, 1024, 1024, 1048576, 0, 1048576);
    k_transpose2<<<dim3(64, 32, 4), dim3(32, 8), 0, stream>>>(
        wkv, lnxw, wkvxT, wkvlT, 1024, 2048, 2097152, 1024, 2097152);
    k_transpose<<<dim3(32, 32, 4), dim3(32, 8), 0, stream>>>(
        wo, nullptr, woT, 1024, 1024, 1048576, 0, 1048576);
    k_transpose<<<dim3(128, 32, 4), dim3(32, 8), 0, stream>>>(
        ffw1, nullptr, ffw1T, 1024, 4096, 4194304, 0, 4194304);
    k_transpose<<<dim3(32, 128, 4), dim3(32, 8), 0, stream>>>(
        ffw2, nullptr, ffw2T, 4096, 1024, 4194304, 0, 4194304);
    k_bias1<<<dim3(8, 16, 4), 256, 0, stream>>>(wkv, lnxb, bxp, 2097152, 1024, 32768);
    k_bias2<<<dim3(8, 4), 256, 0, stream>>>(bxp, bx, 32768, 2048);
  }

  for (int l = 0; l < 4; l++) {
    const float* wq_l  = wq  + (size_t)l * 1024 * 1024;
    const float* wkv_l = wkv + (size_t)l * 1024 * 2048;
    const float* wo_l  = wo  + (size_t)l * 1024 * 1024;
    const float* w1_l  = ffw1 + (size_t)l * 1024 * 4096;
    const float* w2_l  = ffw2 + (size_t)l * 4096 * 1024;

    if (!hoist) {
      k_transpose<<<dim3(32, 32, 1), dim3(32, 8), 0, stream>>>(
          wq_l, nullptr, wqT, 1024, 1024, 0, 0, 0);
      k_transpose2<<<dim3(64, 32, 1), dim3(32, 8), 0, stream>>>(
          wkv_l, lnxw + l * 1024, wkvxT, wkvlT, 1024, 2048, 0, 0, 0);
      k_transpose<<<dim3(32, 32, 1), dim3(32, 8), 0, stream>>>(
          wo_l, nullptr, woT, 1024, 1024, 0, 0, 0);
      k_transpose<<<dim3(128, 32, 1), dim3(32, 8), 0, stream>>>(
          w1_l, nullptr, ffw1T, 1024, 4096, 0, 0, 0);
      k_transpose<<<dim3(32, 128, 1), dim3(32, 8), 0, stream>>>(
          w2_l, nullptr, ffw2T, 4096, 1024, 0, 0, 0);
      k_bias1<<<dim3(8, 16, 1), 256, 0, stream>>>(wkv_l, lnxb + l * 1024, bxp, 0, 0, 0);
      k_bias2<<<dim3(8, 1), 256, 0, stream>>>(bxp, bx, 0, 0);
    }
    const u16* wqT_l   = wqT   + (hoist ? (size_t)l * 1048576 : 0);
    const u16* wkvxT_l = wkvxT + (hoist ? (size_t)l * 2097152 : 0);
    const u16* wkvlT_l = wkvlT + (hoist ? (size_t)l * 2097152 : 0);
    const u16* woT_l   = woT   + (hoist ? (size_t)l * 1048576 : 0);
    const u16* ffw1T_l = ffw1T + (hoist ? (size_t)l * 4194304 : 0);
    const u16* ffw2T_l = ffw2T + (hoist ? (size_t)l * 4194304 : 0);
    const float* bx_l  = bx    + (hoist ? (size_t)l * 2048 : 0);

    k_lnrow<<<544, 256, 0, stream>>>(lat, lnlw + l * 1024, lnlb + l * 1024, lnlat);

    gemm_kv<<<1024, 512, 65536, stream>>>(xp_hat, wkvxT_l, kvb, bx_l);
    gemm_two<<<dim3(24, 5), 256, 0, stream>>>(lnlat, wqT_l, wkvlT_l, qb, kvb + (size_t)4096 * 2048);

    k_flash<<<dim3(NJC, 16, 8), 256, 0, stream>>>(qb, kvb, opart, lpart);
    k_comb<<<544, 256, 0, stream>>>(opart, lpart, obf, o2);

    // wo-GEMM: split-K x4 with atomic f32 accumulate into o2 (zeroed by k_comb)
    gemm_nt<3, false><<<dim3(8, 5, 4), 256, 0, stream>>>(
        obf, woT_l, o2, nullptr, 544, 1024, 1024, 1.f, 544, 0, 1024, 256);
    k_attnln<<<544, 256, 0, stream>>>(o2, lat, olnw + l * 1024, olnb + l * 1024,
                                      ffg1 + l * 1024, latg);
    gemm_nt<0, false><<<dim3(32, 5, 1), 256, 0, stream>>>(
        latg, ffw1T_l, hbuf, nullptr, 544, 4096, 1024, 1.f, 544, 0, 4096, 1024);
    k_geluln<<<544, 256, 0, stream>>>(hbuf, ffg2 + l * 4096, hg);
    // ffw2-GEMM: split-K x8, atomic accumulate into lat (residual already there)
    gemm_nt<3, false><<<dim3(8, 5, 8), 256, 0, stream>>>(
        hg, ffw2T_l, lat, nullptr, 544, 1024, 4096, 1.f, 544, 0, 1024, 512);
  }

  hipMemcpyAsync(d_out, lat, (size_t)out_size * 4, hipMemcpyDeviceToDevice, stream);
}

// Round 6
// 1631.240 us; speedup vs baseline: 3.7268x; 3.7268x over previous
//
#include <hip/hip_runtime.h>

typedef __bf16 bf16x8 __attribute__((ext_vector_type(8)));
typedef float f32x4 __attribute__((ext_vector_type(4)));
typedef unsigned short u16;
typedef unsigned int u32;

typedef __attribute__((address_space(3))) u16 lds_u16;
typedef __attribute__((address_space(1))) const u16 glb_u16;

#define NJC 4

__device__ inline float bf2f(u16 u) { union { u32 i; float f; } x; x.i = (u32)u << 16; return x.f; }
__device__ inline u16 f2bf(float f) {
  union { float f; u32 i; } u; u.f = f;
  u32 r = u.i + 0x7fffu + ((u.i >> 16) & 1u);
  return (u16)(r >> 16);
}

__device__ inline float blk_sum256(float v, float* red) {
#pragma unroll
  for (int o = 32; o > 0; o >>= 1) v += __shfl_xor(v, o);
  __syncthreads();
  if ((threadIdx.x & 63) == 0) red[threadIdx.x >> 6] = v;
  __syncthreads();
  return red[0] + red[1] + red[2] + red[3];
}

// ============ kv-projection GEMM: 128x256 tile, 8 waves, target 2 blocks/CU ==========
// R5 proved 2-block/CU residency happens when regs fit (Occupancy 21.8->43.6%) but the
// 256x256 tile's acc[8][4]=128 regs forced a spill. This tile halves the per-wave
// accumulator (acc[4][4]=64) so ~120 combined regs fit the 128 cap for 4 waves/SIMD.
// LDS ring-2 = 48 KiB. NO launch-bounds min arg (R5's was misinterpreted -> 64-reg cap).
__global__ __launch_bounds__(512) void gemm_kv(const u16* __restrict__ A,
                                               const u16* __restrict__ BT,
                                               u16* __restrict__ C,
                                               const float* __restrict__ bias) {
  extern __shared__ __align__(16) u16 lds[];  // [2 slots][A 4096 | B 8192 elems] = 48 KiB
  const int tid = threadIdx.x, l = tid & 63, w = tid >> 6;
  const int wr = w >> 2, wc = w & 3;  // 2 x 4 wave grid; per-wave out 64x64
  int bid = blockIdx.x;
  int swz = (bid & 7) * 256 + (bid >> 3);  // XCD chunking (bijective, 2048%8==0)
  int by = swz >> 3, bx = swz & 7;
  const long m0 = (long)by * 128;
  const int n0 = bx * 256;

  // staging maps (swizzled for conflict-free ds_read_b128); 32-bit offsets save VGPRs
  int srcA;
  {
    int p = tid >> 3, j = tid & 7, jp = j ^ (p & 7);
    int row = (p << 1) | (jp >> 2), cc = jp & 3;
    srcA = row * 1024 + cc * 8;  // m0 folded into Abase
  }
  int srcB[2];
#pragma unroll
  for (int s = 0; s < 2; s++) {
    int g = s * 512 + tid;
    int p = g >> 3, j = g & 7, jp = j ^ (p & 7);
    int row = (p << 1) | (jp >> 2), cc = jp & 3;
    srcB[s] = (n0 + row) * 1024 + cc * 8;
  }
  const u16* Abase = A + m0 * 1024;

  const int rA = l & 15, cch = l >> 4;
  const int R0a = wr * 64 + rA;
  const int aoff = (R0a >> 1) * 64 + (((((R0a & 1) << 2) | cch) ^ ((R0a >> 1) & 7)) << 3);
  const int R0b = wc * 64 + rA;
  const int boff = (R0b >> 1) * 64 + (((((R0b & 1) << 2) | cch) ^ ((R0b >> 1) & 7)) << 3);

  f32x4 acc[4][4] = {};

  auto stage = [&](int t) {
    u16* dst = lds + (t & 1) * 12288;
    int kt = t * 32;
    __builtin_amdgcn_global_load_lds((glb_u16*)(Abase + srcA + kt),
                                     (lds_u16*)(dst + tid * 8), 16, 0, 0);
#pragma unroll
    for (int s = 0; s < 2; s++)
      __builtin_amdgcn_global_load_lds((glb_u16*)(BT + srcB[s] + kt),
                                       (lds_u16*)(dst + 4096 + (s * 512 + tid) * 8), 16, 0, 0);
  };

  // prologue: subtiles 0,1 (3 loads each); wait subtile 0 (leave 1 in flight)
  stage(0); stage(1);
  asm volatile("s_waitcnt vmcnt(3)" ::: "memory");
  __builtin_amdgcn_s_barrier();

  for (int t = 0; t < 32; ++t) {
    const u16* Ab = lds + (t & 1) * 12288;
    const u16* Bb = Ab + 4096;
    bf16x8 af[4], bf[4];
#pragma unroll
    for (int mf = 0; mf < 4; mf++) af[mf] = *(const bf16x8*)(Ab + aoff + mf * 512);
#pragma unroll
    for (int nf = 0; nf < 4; nf++) bf[nf] = *(const bf16x8*)(Bb + boff + nf * 512);
    asm volatile("s_waitcnt lgkmcnt(0)" ::: "memory");
    __builtin_amdgcn_sched_barrier(0);
    __builtin_amdgcn_s_barrier();          // all waves done reading slot t&1
    if (t + 2 < 32) stage(t + 2);          // overwrite freed slot
    __builtin_amdgcn_s_setprio(1);
#pragma unroll
    for (int mf = 0; mf < 4; mf++)
#pragma unroll
      for (int nf = 0; nf < 4; nf++)
        acc[mf][nf] = __builtin_amdgcn_mfma_f32_16x16x32_bf16(af[mf], bf[nf], acc[mf][nf], 0, 0, 0);
    __builtin_amdgcn_s_setprio(0);
    if (t + 2 < 32)      asm volatile("s_waitcnt vmcnt(3)" ::: "memory");  // t+1 landed
    else if (t + 1 < 32) asm volatile("s_waitcnt vmcnt(0)" ::: "memory");
    __builtin_amdgcn_sched_barrier(0);
    __builtin_amdgcn_s_barrier();
  }

  const long batch_off = (m0 >> 12) * ((long)4164 * 2048);
  const int rb0 = (int)(m0 & 4095) + wr * 64 + ((l >> 4) << 2);
#pragma unroll
  for (int mf = 0; mf < 4; mf++) {
#pragma unroll
    for (int nf = 0; nf < 4; nf++) {
      int col = n0 + wc * 64 + nf * 16 + (l & 15);
      float bv = bias[col];
#pragma unroll
      for (int rr = 0; rr < 4; rr++) {
        int rloc = rb0 + mf * 16 + rr;
        C[batch_off + (long)rloc * 2048 + col] = f2bf(acc[mf][nf][rr] + bv);
      }
    }
  }
}

// ---------------- general GEMM (small shapes): C = alpha*A@BT^T (+bias) -------------
// Ring-2 double-buffered staging with raw s_barrier + counted vmcnt.
// MODE 0: f32 store; 1: bf16 store; 2: f32 += (single writer); 3: f32 atomicAdd
template <int MODE, bool BIAS>
__global__ __launch_bounds__(256) void gemm_nt(const u16* __restrict__ A,
                                               const u16* __restrict__ BT,
                                               void* __restrict__ C,
                                               const float* __restrict__ bias,
                                               int M, int N, int K, float alpha,
                                               int RB, long BS, int LDC, int KC) {
  __shared__ __align__(16) u16 As[2][128 * 64];
  __shared__ __align__(16) u16 Bs[2][128 * 64];
  int m0 = blockIdx.y * 128, n0 = blockIdx.x * 128;
  int tid = threadIdx.x;
  int l = tid & 63, w = tid >> 6;
  int wr = w >> 1, wc = w & 1;
  f32x4 acc[4][4] = {};

  const int srow = l >> 3;
  const int scol = (l & 7) * 8;
  const int Mc = M - 1;
  const int k0 = blockIdx.z * KC;
  const int k1 = (k0 + KC < K) ? k0 + KC : K;

  auto stage = [&](int kt, int pb) {
#pragma unroll
    for (int r = 0; r < 4; r++) {
      int rowg = (r * 4 + w) * 8;
      int arow = m0 + rowg + srow; if (arow > Mc) arow = Mc;
      int brow = n0 + rowg + srow;
      const u16* ag = A + (long)arow * K + kt + scol;
      const u16* bg = BT + (long)brow * K + kt + scol;
      __builtin_amdgcn_global_load_lds((glb_u16*)ag, (lds_u16*)(&As[pb][rowg * 64]), 16, 0, 0);
      __builtin_amdgcn_global_load_lds((glb_u16*)bg, (lds_u16*)(&Bs[pb][rowg * 64]), 16, 0, 0);
    }
  };

  stage(k0, 0);
  int it = 0;
  for (int kt = k0; kt < k1; kt += 64, ++it) {
    const int pb = it & 1;
    const bool more = (kt + 64) < k1;
    if (more) stage(kt + 64, pb ^ 1);
    if (more) asm volatile("s_waitcnt vmcnt(8)" ::: "memory");
    else      asm volatile("s_waitcnt vmcnt(0)" ::: "memory");
    __builtin_amdgcn_sched_barrier(0);
    __builtin_amdgcn_s_barrier();
    const u16* Ab = &As[pb][0];
    const u16* Bb = &Bs[pb][0];
#pragma unroll
    for (int kk = 0; kk < 2; kk++) {
      bf16x8 af[4], bfv[4];
#pragma unroll
      for (int mf = 0; mf < 4; mf++)
        af[mf] = *(const bf16x8*)(Ab + (wr * 64 + mf * 16 + (l & 15)) * 64 + kk * 32 + (l >> 4) * 8);
#pragma unroll
      for (int nf = 0; nf < 4; nf++)
        bfv[nf] = *(const bf16x8*)(Bb + (wc * 64 + nf * 16 + (l & 15)) * 64 + kk * 32 + (l >> 4) * 8);
#pragma unroll
      for (int mf = 0; mf < 4; mf++)
#pragma unroll
        for (int nf = 0; nf < 4; nf++)
          acc[mf][nf] = __builtin_amdgcn_mfma_f32_16x16x32_bf16(af[mf], bfv[nf], acc[mf][nf], 0, 0, 0);
    }
    __builtin_amdgcn_sched_barrier(0);
    __builtin_amdgcn_s_barrier();
  }

#pragma unroll
  for (int mf = 0; mf < 4; mf++) {
#pragma unroll
    for (int nf = 0; nf < 4; nf++) {
      int col = n0 + wc * 64 + nf * 16 + (l & 15);
      float bv = 0.f;
      if (BIAS) bv = bias[col];
#pragma unroll
      for (int rr = 0; rr < 4; rr++) {
        int row = m0 + wr * 64 + mf * 16 + (l >> 4) * 4 + rr;
        if (row < M) {
          float v = acc[mf][nf][rr] * alpha + bv;
          long off = (long)(row / RB) * BS + (long)(row % RB) * LDC + col;
          if (MODE == 0) ((float*)C)[off] = v;
          else if (MODE == 1) ((u16*)C)[off] = f2bf(v);
          else if (MODE == 2) ((float*)C)[off] += v;
          else atomicAdd(&((float*)C)[off], v);
        }
      }
    }
  }
}

// ---------------- fused q-proj + kvlat-proj (both read lnlat, M=544, K=1024) --------
__global__ __launch_bounds__(256) void gemm_two(const u16* __restrict__ A,
                                                const u16* __restrict__ BTq,
                                                const u16* __restrict__ BTkv,
                                                u16* __restrict__ Cq,
                                                u16* __restrict__ Ckv) {
  __shared__ __align__(16) u16 As[2][128 * 64];
  __shared__ __align__(16) u16 Bs[2][128 * 64];
  const int K = 1024, M = 544;
  int bxr = blockIdx.x;
  const u16* BT; u16* C; float alpha; int RB; long BS; int LDC; int n0;
  if (bxr < 8) { BT = BTq;  C = Cq;  alpha = 0.125f; RB = 544; BS = 0;                 LDC = 1024; n0 = bxr * 128; }
  else         { BT = BTkv; C = Ckv; alpha = 1.f;    RB = 68;  BS = (long)4164 * 2048; LDC = 2048; n0 = (bxr - 8) * 128; }
  int m0 = blockIdx.y * 128;
  int tid = threadIdx.x;
  int l = tid & 63, w = tid >> 6;
  int wr = w >> 1, wc = w & 1;
  f32x4 acc[4][4] = {};

  const int srow = l >> 3;
  const int scol = (l & 7) * 8;
  const int Mc = M - 1;

  auto stage = [&](int kt, int pb) {
#pragma unroll
    for (int r = 0; r < 4; r++) {
      int rowg = (r * 4 + w) * 8;
      int arow = m0 + rowg + srow; if (arow > Mc) arow = Mc;
      int brow = n0 + rowg + srow;
      const u16* ag = A + (long)arow * K + kt + scol;
      const u16* bg = BT + (long)brow * K + kt + scol;
      __builtin_amdgcn_global_load_lds((glb_u16*)ag, (lds_u16*)(&As[pb][rowg * 64]), 16, 0, 0);
      __builtin_amdgcn_global_load_lds((glb_u16*)bg, (lds_u16*)(&Bs[pb][rowg * 64]), 16, 0, 0);
    }
  };

  stage(0, 0);
  int it = 0;
  for (int kt = 0; kt < K; kt += 64, ++it) {
    const int pb = it & 1;
    const bool more = (kt + 64) < K;
    if (more) stage(kt + 64, pb ^ 1);
    if (more) asm volatile("s_waitcnt vmcnt(8)" ::: "memory");
    else      asm volatile("s_waitcnt vmcnt(0)" ::: "memory");
    __builtin_amdgcn_sched_barrier(0);
    __builtin_amdgcn_s_barrier();
    const u16* Ab = &As[pb][0];
    const u16* Bb = &Bs[pb][0];
#pragma unroll
    for (int kk = 0; kk < 2; kk++) {
      bf16x8 af[4], bfv[4];
#pragma unroll
      for (int mf = 0; mf < 4; mf++)
        af[mf] = *(const bf16x8*)(Ab + (wr * 64 + mf * 16 + (l & 15)) * 64 + kk * 32 + (l >> 4) * 8);
#pragma unroll
      for (int nf = 0; nf < 4; nf++)
        bfv[nf] = *(const bf16x8*)(Bb + (wc * 64 + nf * 16 + (l & 15)) * 64 + kk * 32 + (l >> 4) * 8);
#pragma unroll
      for (int mf = 0; mf < 4; mf++)
#pragma unroll
        for (int nf = 0; nf < 4; nf++)
          acc[mf][nf] = __builtin_amdgcn_mfma_f32_16x16x32_bf16(af[mf], bfv[nf], acc[mf][nf], 0, 0, 0);
    }
    __builtin_amdgcn_sched_barrier(0);
    __builtin_amdgcn_s_barrier();
  }

#pragma unroll
  for (int mf = 0; mf < 4; mf++) {
#pragma unroll
    for (int nf = 0; nf < 4; nf++) {
      int col = n0 + wc * 64 + nf * 16 + (l & 15);
#pragma unroll
      for (int rr = 0; rr < 4; rr++) {
        int row = m0 + wr * 64 + mf * 16 + (l >> 4) * 4 + rr;
        if (row < M) {
          float v = acc[mf][nf][rr] * alpha;
          long off = (long)(row / RB) * BS + (long)(row % RB) * LDC + col;
          C[off] = f2bf(v);
        }
      }
    }
  }
}

// ---------------- transpose + optional row-scale + f32->bf16 (batched over z) -------
__global__ __launch_bounds__(256) void k_transpose(const float* __restrict__ W,
                                                   const float* __restrict__ scale,
                                                   u16* __restrict__ WT, int K, int N,
                                                   long wls, long sls, long tls) {
  __shared__ float tile[32][33];
  int z = blockIdx.z;
  W += (long)z * wls; WT += (long)z * tls;
  if (scale) scale += (long)z * sls;
  int n0 = blockIdx.x * 32, k0 = blockIdx.y * 32;
  int x = threadIdx.x, y = threadIdx.y;
#pragma unroll
  for (int i = 0; i < 4; i++) tile[y + 8 * i][x] = W[(long)(k0 + y + 8 * i) * N + n0 + x];
  __syncthreads();
#pragma unroll
  for (int i = 0; i < 4; i++) {
    int k = k0 + x, n = n0 + y + 8 * i;
    float v = tile[x][y + 8 * i];
    if (scale) v *= scale[k];
    WT[(long)n * K + k] = f2bf(v);
  }
}

__global__ __launch_bounds__(256) void k_transpose2(const float* __restrict__ W,
                                                    const float* __restrict__ scale,
                                                    u16* __restrict__ WTs,
                                                    u16* __restrict__ WTp, int K, int N,
                                                    long wls, long sls, long tls) {
  __shared__ float tile[32][33];
  int z = blockIdx.z;
  W += (long)z * wls; scale += (long)z * sls;
  WTs += (long)z * tls; WTp += (long)z * tls;
  int n0 = blockIdx.x * 32, k0 = blockIdx.y * 32;
  int x = threadIdx.x, y = threadIdx.y;
#pragma unroll
  for (int i = 0; i < 4; i++) tile[y + 8 * i][x] = W[(long)(k0 + y + 8 * i) * N + n0 + x];
  __syncthreads();
#pragma unroll
  for (int i = 0; i < 4; i++) {
    int k = k0 + x, n = n0 + y + 8 * i;
    float v = tile[x][y + 8 * i];
    WTp[(long)n * K + k] = f2bf(v);
    WTs[(long)n * K + k] = f2bf(v * scale[k]);
  }
}

// ---------------- xp_hat = normalize(x + pos_emb) per row, bf16 ---------------------
__global__ __launch_bounds__(256) void k_xphat(const float* __restrict__ x,
                                               const float* __restrict__ pos,
                                               u16* __restrict__ xph) {
  __shared__ float red[4];
  long row = blockIdx.x;
  int n = blockIdx.x & 4095;
  const float* xr = x + row * 1024;
  const float* pr = pos + (long)n * 1024;
  float v[4]; float s = 0.f;
#pragma unroll
  for (int i = 0; i < 4; i++) { int c = threadIdx.x + i * 256; v[i] = xr[c] + pr[c]; s += v[i]; }
  float mean = blk_sum256(s, red) * (1.f / 1024.f);
  float s2 = 0.f;
#pragma unroll
  for (int i = 0; i < 4; i++) { float d = v[i] - mean; s2 += d * d; }
  float rs = rsqrtf(blk_sum256(s2, red) * (1.f / 1024.f) + 1e-5f);
#pragma unroll
  for (int i = 0; i < 4; i++) xph[row * 1024 + threadIdx.x + i * 256] = f2bf((v[i] - mean) * rs);
}

// ---------------- mp: column sums of x over n ---------------------------------------
__global__ __launch_bounds__(256) void k_mp(const float* __restrict__ x, float* __restrict__ macc) {
  int d = blockIdx.x * 256 + threadIdx.x;
  int nc = blockIdx.y, b = blockIdx.z;
  const float* xb = x + (long)b * 4096 * 1024;
  float s = 0.f;
  for (int n = nc * 256; n < nc * 256 + 256; n++) s += xb[(long)n * 1024 + d];
  atomicAdd(&macc[b * 1024 + d], s);
}

__global__ __launch_bounds__(256) void k_mphat(const float* __restrict__ macc,
                                               const float* __restrict__ g,
                                               float* __restrict__ mphat) {
  __shared__ float red[4];
  int b = blockIdx.x;
  float v[4]; float s = 0.f;
#pragma unroll
  for (int i = 0; i < 4; i++) { v[i] = macc[b * 1024 + threadIdx.x + i * 256] * (1.f / 4096.f); s += v[i]; }
  float mean = blk_sum256(s, red) * (1.f / 1024.f);
  float s2 = 0.f;
#pragma unroll
  for (int i = 0; i < 4; i++) { float d = v[i] - mean; s2 += d * d; }
  float rs = rsqrtf(blk_sum256(s2, red) * (1.f / 1024.f) + 1e-5f);
#pragma unroll
  for (int i = 0; i < 4; i++) {
    int c = threadIdx.x + i * 256;
    mphat[b * 1024 + c] = (v[i] - mean) * rs * g[c];
  }
}

__global__ __launch_bounds__(256) void k_mplat(const float* __restrict__ mphat,
                                               const float* __restrict__ w,
                                               const float* __restrict__ bias,
                                               float* __restrict__ lat) {
  int j = blockIdx.x * 256 + threadIdx.x;
  int b = blockIdx.y;
  const float* mh = mphat + b * 1024;
  float s = bias[j];
  for (int k = 0; k < 1024; k++) s += mh[k] * w[(long)k * 4096 + j];
  lat[(long)b * 69632 + (j >> 10) * 1024 + (j & 1023)] = s;
}

__global__ __launch_bounds__(256) void k_latfill(const float* __restrict__ latents,
                                                 float* __restrict__ lat) {
  int idx = blockIdx.x * 256 + threadIdx.x;
  int b = idx >> 16, rest = idx & 65535;
  lat[(long)b * 69632 + 4096 + rest] = latents[rest];
}

// ---------------- lnlat = LN(lat)*w+b  -> bf16 -------------------------------------
__global__ __launch_bounds__(256) void k_lnrow(const float* __restrict__ in,
                                               const float* __restrict__ w,
                                               const float* __restrict__ bb,
                                               u16* __restrict__ out) {
  __shared__ float red[4];
  long row = blockIdx.x;
  const float* xr = in + row * 1024;
  float v[4]; float s = 0.f;
#pragma unroll
  for (int i = 0; i < 4; i++) { v[i] = xr[threadIdx.x + i * 256]; s += v[i]; }
  float mean = blk_sum256(s, red) * (1.f / 1024.f);
  float s2 = 0.f;
#pragma unroll
  for (int i = 0; i < 4; i++) { float d = v[i] - mean; s2 += d * d; }
  float rs = rsqrtf(blk_sum256(s2, red) * (1.f / 1024.f) + 1e-5f);
#pragma unroll
  for (int i = 0; i < 4; i++) {
    int c = threadIdx.x + i * 256;
    out[row * 1024 + c] = f2bf((v[i] - mean) * rs * w[c] + bb[c]);
  }
}

// ---------------- bias fold (batched over z = layer) --------------------------------
__global__ __launch_bounds__(256) void k_bias1(const float* __restrict__ wkv,
                                               const float* __restrict__ lnxb,
                                               float* __restrict__ bxp,
                                               long wls, long bls, long pls) {
  int z = blockIdx.z;
  wkv += (long)z * wls; lnxb += (long)z * bls; bxp += (long)z * pls;
  int n = blockIdx.x * 256 + threadIdx.x;
  int kc = blockIdx.y;
  float s = 0.f;
  for (int k = kc * 64; k < kc * 64 + 64; k++) s += lnxb[k] * wkv[(long)k * 2048 + n];
  bxp[kc * 2048 + n] = s;
}
__global__ __launch_bounds__(256) void k_bias2(const float* __restrict__ bxp,
                                               float* __restrict__ bx,
                                               long pls, long xls) {
  int z = blockIdx.y;
  bxp += (long)z * pls; bx += (long)z * xls;
  int n = blockIdx.x * 256 + threadIdx.x;
  float s = 0.f;
#pragma unroll
  for (int kc = 0; kc < 16; kc++) s += bxp[kc * 2048 + n];
  bx[n] = s;
}

// ---------------- MFMA flash attention, T14 software-pipelined ----------------------
__global__ __launch_bounds__(256) void k_flash(const u16* __restrict__ q,
                                               const u16* __restrict__ kv,
                                               float* __restrict__ opart,
                                               float* __restrict__ lpart) {
  int c = blockIdx.x, h = blockIdx.y, b = blockIdx.z;
  int tid = threadIdx.x, l = tid & 63, w = tid >> 6;

  __shared__ __align__(16) char smem_raw[46080];
  u16 (*Vt)[64][40] = reinterpret_cast<u16(*)[64][40]>(smem_raw);
  u16 (*Pl)[80][40] = reinterpret_cast<u16(*)[80][40]>(smem_raw + 20480);
  float (*O_s)[64] = reinterpret_cast<float(*)[64]>(smem_raw);
  float* l_s = reinterpret_cast<float*>(smem_raw + 20480);

  const int JCH = 1041;
  const int jstart = c * JCH;
  const int jend = (c == NJC - 1) ? 4164 : jstart + JCH;
  const long kvbase = (long)b * 4164 * 2048;
  const u16* Kp = kv + kvbase + h * 64;
  const u16* Vp = kv + kvbase + 1024 + h * 64;

  bf16x8 qf[5][2];
#pragma unroll
  for (int it = 0; it < 5; it++) {
    int qi = it * 16 + (l & 15); if (qi > 67) qi = 67;
    const u16* qrow = q + ((long)(b * 68 + qi) * 1024 + h * 64 + (l >> 4) * 8);
    qf[it][0] = *(const bf16x8*)(qrow);
    qf[it][1] = *(const bf16x8*)(qrow + 32);
  }

  f32x4 Of[5][4] = {};
  float lac[5] = {0.f, 0.f, 0.f, 0.f, 0.f};

  auto loadV = [&](int j0, uint4 vv[4]) {
#pragma unroll
    for (int t = 0; t < 4; t++) {
      int vj = j0 + (l & 31);
      int vjc = vj < 4163 ? vj : 4163;
      int vd = (l >> 5) * 8 + t * 16;
      vv[t] = *(const uint4*)(Vp + (long)vjc * 2048 + vd);
    }
  };
  auto loadK = [&](int j0, bf16x8& a00, bf16x8& a01, bf16x8& a10, bf16x8& a11) {
    const u16* kr0 = Kp + (long)(j0 + (l & 15)) * 2048 + (l >> 4) * 8;
    a00 = *(const bf16x8*)(kr0);
    a01 = *(const bf16x8*)(kr0 + 32);
    const u16* kr1 = Kp + (long)(j0 + 16 + (l & 15)) * 2048 + (l >> 4) * 8;
    a10 = *(const bf16x8*)(kr1);
    a11 = *(const bf16x8*)(kr1 + 32);
  };

  const int jbeg = jstart + w * 32;
  uint4 vr[4];
  bf16x8 k0a, k0b, k1a, k1b;
  if (jbeg < jend) { loadV(jbeg, vr); loadK(jbeg, k0a, k0b, k1a, k1b); }

  for (int j0 = jbeg; j0 < jend; j0 += 4 * 32) {
#pragma unroll
    for (int t = 0; t < 4; t++) {
      int vd = (l >> 5) * 8 + t * 16;
      union { uint4 q4; u16 s[8]; } uu; uu.q4 = vr[t];
#pragma unroll
      for (int e = 0; e < 8; e++) Vt[w][vd + e][l & 31] = uu.s[e];
    }
    f32x4 sf[2][5];
#pragma unroll
    for (int it = 0; it < 5; it++) {
      f32x4 d0 = {};
      d0 = __builtin_amdgcn_mfma_f32_16x16x32_bf16(k0a, qf[it][0], d0, 0, 0, 0);
      d0 = __builtin_amdgcn_mfma_f32_16x16x32_bf16(k0b, qf[it][1], d0, 0, 0, 0);
      sf[0][it] = d0;
      f32x4 d1 = {};
      d1 = __builtin_amdgcn_mfma_f32_16x16x32_bf16(k1a, qf[it][0], d1, 0, 0, 0);
      d1 = __builtin_amdgcn_mfma_f32_16x16x32_bf16(k1b, qf[it][1], d1, 0, 0, 0);
      sf[1][it] = d1;
    }
    int jn = j0 + 4 * 32;
    bool more = jn < jend;
    uint4 vr2[4];
    bf16x8 n0a, n0b, n1a, n1b;
    if (more) { loadV(jn, vr2); loadK(jn, n0a, n0b, n1a, n1b); }
#pragma unroll
    for (int jt = 0; jt < 2; jt++) {
      int jb = j0 + jt * 16 + (l >> 4) * 4;
#pragma unroll
      for (int it = 0; it < 5; it++) {
        u16 pk[4];
#pragma unroll
        for (int r = 0; r < 4; r++) {
          float p = (jb + r < jend) ? __expf(sf[jt][it][r]) : 0.f;
          lac[it] += p;
          pk[r] = f2bf(p);
        }
        *(uint2*)(&Pl[w][it * 16 + (l & 15)][jt * 16 + (l >> 4) * 4]) = *(const uint2*)pk;
      }
    }
#pragma unroll
    for (int it = 0; it < 5; it++) {
      bf16x8 pa = *(const bf16x8*)(&Pl[w][it * 16 + (l & 15)][(l >> 4) * 8]);
#pragma unroll
      for (int dt = 0; dt < 4; dt++) {
        bf16x8 vb = *(const bf16x8*)(&Vt[w][dt * 16 + (l & 15)][(l >> 4) * 8]);
        Of[it][dt] = __builtin_amdgcn_mfma_f32_16x16x32_bf16(pa, vb, Of[it][dt], 0, 0, 0);
      }
    }
    if (more) {
      vr[0] = vr2[0]; vr[1] = vr2[1]; vr[2] = vr2[2]; vr[3] = vr2[3];
      k0a = n0a; k0b = n0b; k1a = n1a; k1b = n1b;
    }
  }

  __syncthreads();
  for (int u = tid; u < 80 * 64; u += 256) ((float*)O_s)[u] = 0.f;
  if (tid < 80) l_s[tid] = 0.f;
  __syncthreads();
#pragma unroll
  for (int it = 0; it < 5; it++) {
    float v = lac[it];
    v += __shfl_xor(v, 16);
    v += __shfl_xor(v, 32);
    if (l < 16) atomicAdd(&l_s[it * 16 + l], v);
#pragma unroll
    for (int dt = 0; dt < 4; dt++) {
#pragma unroll
      for (int r = 0; r < 4; r++) {
        int i = it * 16 + (l >> 4) * 4 + r;
        int d = dt * 16 + (l & 15);
        atomicAdd(&O_s[i][d], Of[it][dt][r]);
      }
    }
  }
  __syncthreads();
  long base = (long)((b * 16 + h) * NJC + c);
  for (int u = tid; u < 68 * 64; u += 256)
    opart[base * 68 * 64 + u] = O_s[u >> 6][u & 63];
  if (tid < 68) lpart[base * 68 + tid] = l_s[tid];
}

// ---------------- combine partials -> obf bf16; also zero o2 for the wo split-K ----
__global__ __launch_bounds__(256) void k_comb(const float* __restrict__ opart,
                                              const float* __restrict__ lpart,
                                              u16* __restrict__ obf,
                                              float* __restrict__ o2z) {
  int r = blockIdx.x;
  int b = r / 68, i = r % 68;
#pragma unroll
  for (int it = 0; it < 4; it++) {
    int col = threadIdx.x + it * 256;
    int h = col >> 6, d = col & 63;
    long bh = (long)(b * 16 + h) * NJC;
    float os = 0.f, ls = 0.f;
    for (int cc = 0; cc < NJC; cc++) {
      os += opart[(bh + cc) * 68 * 64 + (long)i * 64 + d];
      ls += lpart[(bh + cc) * 68 + i];
    }
    obf[(long)r * 1024 + col] = f2bf(os / ls);
    o2z[(long)r * 1024 + col] = 0.f;
  }
}

// ---------------- o-path: lat += LN(o2)*w+b ; latg = LN_g(lat_new)*g ----------------
__global__ __launch_bounds__(256) void k_attnln(const float* __restrict__ o2,
                                                float* __restrict__ lat,
                                                const float* __restrict__ w,
                                                const float* __restrict__ bb,
                                                const float* __restrict__ g,
                                                u16* __restrict__ latg) {
  __shared__ float red[4];
  long row = blockIdx.x;
  const float* xr = o2 + row * 1024;
  float* lr = lat + row * 1024;
  float v[4]; float s = 0.f;
#pragma unroll
  for (int i = 0; i < 4; i++) { v[i] = xr[threadIdx.x + i * 256]; s += v[i]; }
  float mean = blk_sum256(s, red) * (1.f / 1024.f);
  float s2 = 0.f;
#pragma unroll
  for (int i = 0; i < 4; i++) { float d = v[i] - mean; s2 += d * d; }
  float rs = rsqrtf(blk_sum256(s2, red) * (1.f / 1024.f) + 1e-5f);
  float lv[4]; float sl = 0.f;
#pragma unroll
  for (int i = 0; i < 4; i++) {
    int c = threadIdx.x + i * 256;
    float t = (v[i] - mean) * rs * w[c] + bb[c];
    lv[i] = lr[c] + t;
    lr[c] = lv[i];
    sl += lv[i];
  }
  float mean2 = blk_sum256(sl, red) * (1.f / 1024.f);
  float s22 = 0.f;
#pragma unroll
  for (int i = 0; i < 4; i++) { float d = lv[i] - mean2; s22 += d * d; }
  float rs2 = rsqrtf(blk_sum256(s22, red) * (1.f / 1024.f) + 1e-5f);
#pragma unroll
  for (int i = 0; i < 4; i++) {
    int c = threadIdx.x + i * 256;
    latg[row * 1024 + c] = f2bf((lv[i] - mean2) * rs2 * g[c]);
  }
}

// ---------------- FF mid: hg = LN_g(gelu(h))*g2 -------------------------------------
__global__ __launch_bounds__(256) void k_geluln(const float* __restrict__ hin,
                                                const float* __restrict__ g,
                                                u16* __restrict__ out) {
  __shared__ float red[4];
  long row = blockIdx.x;
  const float* xr = hin + row * 4096;
  float v[16]; float s = 0.f;
#pragma unroll
  for (int i = 0; i < 16; i++) {
    int c = threadIdx.x + i * 256;
    float u = xr[c];
    u = 0.5f * u * (1.f + erff(u * 0.70710678118f));
    v[i] = u; s += u;
  }
  float mean = blk_sum256(s, red) * (1.f / 4096.f);
  float s2 = 0.f;
#pragma unroll
  for (int i = 0; i < 16; i++) { float d = v[i] - mean; s2 += d * d; }
  float rs = rsqrtf(blk_sum256(s2, red) * (1.f / 4096.f) + 1e-5f);
#pragma unroll
  for (int i = 0; i < 16; i++) {
    int c = threadIdx.x + i * 256;
    out[row * 4096 + c] = f2bf((v[i] - mean) * rs * g[c]);
  }
}

extern "C" void kernel_launch(void* const* d_in, const int* in_sizes, int n_in,
                              void* d_out, int out_size, void* d_ws, size_t ws_size,
                              hipStream_t stream) {
  const float* x    = (const float*)d_in[0];
  const float* pos  = (const float*)d_in[1];
  const float* lats = (const float*)d_in[2];
  const float* mplng= (const float*)d_in[3];
  const float* mpw  = (const float*)d_in[4];
  const float* mpb  = (const float*)d_in[5];
  const float* lnxw = (const float*)d_in[6];
  const float* lnxb = (const float*)d_in[7];
  const float* lnlw = (const float*)d_in[8];
  const float* lnlb = (const float*)d_in[9];
  const float* wq   = (const float*)d_in[10];
  const float* wkv  = (const float*)d_in[11];
  const float* wo   = (const float*)d_in[12];
  const float* olnw = (const float*)d_in[13];
  const float* olnb = (const float*)d_in[14];
  const float* ffg1 = (const float*)d_in[15];
  const float* ffw1 = (const float*)d_in[16];
  const float* ffg2 = (const float*)d_in[17];
  const float* ffw2 = (const float*)d_in[18];

  char* ws = (char*)d_ws;
  size_t off = 0;
  auto take = [&](size_t n) -> char* {
    off = (off + 255) & ~(size_t)255;
    char* p = ws + off; off += n; return p;
  };
  float* mp_acc = (float*)take(8 * 1024 * 4);
  float* mp_hat = (float*)take(8 * 1024 * 4);
  u16*   xp_hat = (u16*)take((size_t)8 * 4096 * 1024 * 2);
  float* lat    = (float*)take((size_t)8 * 68 * 1024 * 4);
  u16*   lnlat  = (u16*)take((size_t)544 * 1024 * 2);
  u16*   qb     = (u16*)take((size_t)544 * 1024 * 2);
  u16*   kvb    = (u16*)take(((size_t)8 * 4164 + 64) * 2048 * 2);
  float* opart  = (float*)take((size_t)128 * NJC * 68 * 64 * 4);
  float* lpart  = (float*)take((size_t)128 * NJC * 68 * 4);
  u16*   obf    = (u16*)take((size_t)544 * 1024 * 2);
  float* o2     = (float*)take((size_t)544 * 1024 * 4);
  u16*   latg   = (u16*)take((size_t)544 * 1024 * 2);
  float* hbuf   = (float*)take((size_t)544 * 4096 * 4);
  u16*   hg     = (u16*)take((size_t)544 * 4096 * 2);

  // weight buffers: try 4-layer-resident (hoisted prep); fall back to per-layer slots
  size_t fixed_off = off;
  u16 *wqT, *wkvxT, *wkvlT, *woT, *ffw1T, *ffw2T;
  float *bx, *bxp;
  auto alloc_w = [&](size_t rep) {
    wqT   = (u16*)take(rep * (size_t)1024 * 1024 * 2);
    wkvxT = (u16*)take(rep * (size_t)2048 * 1024 * 2);
    wkvlT = (u16*)take(rep * (size_t)2048 * 1024 * 2);
    woT   = (u16*)take(rep * (size_t)1024 * 1024 * 2);
    ffw1T = (u16*)take(rep * (size_t)4096 * 1024 * 2);
    ffw2T = (u16*)take(rep * (size_t)4096 * 1024 * 2);
    bx    = (float*)take(rep * 2048 * 4);
    bxp   = (float*)take(rep * 16 * 2048 * 4);
  };
  alloc_w(4);
  bool hoist = off <= ws_size;
  if (!hoist) { off = fixed_off; alloc_w(1); }

  const long KV_BS = (long)4164 * 2048;

  // ---- precompute ----
  hipMemsetAsync(mp_acc, 0, 8 * 1024 * 4, stream);
  k_xphat<<<32768, 256, 0, stream>>>(x, pos, xp_hat);
  k_mp<<<dim3(4, 16, 8), 256, 0, stream>>>(x, mp_acc);
  k_mphat<<<8, 256, 0, stream>>>(mp_acc, mplng, mp_hat);
  k_mplat<<<dim3(16, 8), 256, 0, stream>>>(mp_hat, mpw, mpb, lat);
  k_latfill<<<2048, 256, 0, stream>>>(lats, lat);

  if (hoist) {
    k_transpose<<<dim3(32, 32, 4), dim3(32, 8), 0, stream>>>(
        wq, nullptr, wqT, 1024, 1024, 1048576, 0, 1048576);
    k_transpose2<<<dim3(64, 32, 4), dim3(32, 8), 0, stream>>>(
        wkv, lnxw, wkvxT, wkvlT, 1024, 2048, 2097152, 1024, 2097152);
    k_transpose<<<dim3(32, 32, 4), dim3(32, 8), 0, stream>>>(
        wo, nullptr, woT, 1024, 1024, 1048576, 0, 1048576);
    k_transpose<<<dim3(128, 32, 4), dim3(32, 8), 0, stream>>>(
        ffw1, nullptr, ffw1T, 1024, 4096, 4194304, 0, 4194304);
    k_transpose<<<dim3(32, 128, 4), dim3(32, 8), 0, stream>>>(
        ffw2, nullptr, ffw2T, 4096, 1024, 4194304, 0, 4194304);
    k_bias1<<<dim3(8, 16, 4), 256, 0, stream>>>(wkv, lnxb, bxp, 2097152, 1024, 32768);
    k_bias2<<<dim3(8, 4), 256, 0, stream>>>(bxp, bx, 32768, 2048);
  }

  for (int l = 0; l < 4; l++) {
    const float* wq_l  = wq  + (size_t)l * 1024 * 1024;
    const float* wkv_l = wkv + (size_t)l * 1024 * 2048;
    const float* wo_l  = wo  + (size_t)l * 1024 * 1024;
    const float* w1_l  = ffw1 + (size_t)l * 1024 * 4096;
    const float* w2_l  = ffw2 + (size_t)l * 4096 * 1024;

    if (!hoist) {
      k_transpose<<<dim3(32, 32, 1), dim3(32, 8), 0, stream>>>(
          wq_l, nullptr, wqT, 1024, 1024, 0, 0, 0);
      k_transpose2<<<dim3(64, 32, 1), dim3(32, 8), 0, stream>>>(
          wkv_l, lnxw + l * 1024, wkvxT, wkvlT, 1024, 2048, 0, 0, 0);
      k_transpose<<<dim3(32, 32, 1), dim3(32, 8), 0, stream>>>(
          wo_l, nullptr, woT, 1024, 1024, 0, 0, 0);
      k_transpose<<<dim3(128, 32, 1), dim3(32, 8), 0, stream>>>(
          w1_l, nullptr, ffw1T, 1024, 4096, 0, 0, 0);
      k_transpose<<<dim3(32, 128, 1), dim3(32, 8), 0, stream>>>(
          w2_l, nullptr, ffw2T, 4096, 1024, 0, 0, 0);
      k_bias1<<<dim3(8, 16, 1), 256, 0, stream>>>(wkv_l, lnxb + l * 1024, bxp, 0, 0, 0);
      k_bias2<<<dim3(8, 1), 256, 0, stream>>>(bxp, bx, 0, 0);
    }
    const u16* wqT_l   = wqT   + (hoist ? (size_t)l * 1048576 : 0);
    const u16* wkvxT_l = wkvxT + (hoist ? (size_t)l * 2097152 : 0);
    const u16* wkvlT_l = wkvlT + (hoist ? (size_t)l * 2097152 : 0);
    const u16* woT_l   = woT   + (hoist ? (size_t)l * 1048576 : 0);
    const u16* ffw1T_l = ffw1T + (hoist ? (size_t)l * 4194304 : 0);
    const u16* ffw2T_l = ffw2T + (hoist ? (size_t)l * 4194304 : 0);
    const float* bx_l  = bx    + (hoist ? (size_t)l * 2048 : 0);

    k_lnrow<<<544, 256, 0, stream>>>(lat, lnlw + l * 1024, lnlb + l * 1024, lnlat);

    gemm_kv<<<2048, 512, 49152, stream>>>(xp_hat, wkvxT_l, kvb, bx_l);
    gemm_two<<<dim3(24, 5), 256, 0, stream>>>(lnlat, wqT_l, wkvlT_l, qb, kvb + (size_t)4096 * 2048);

    k_flash<<<dim3(NJC, 16, 8), 256, 0, stream>>>(qb, kvb, opart, lpart);
    k_comb<<<544, 256, 0, stream>>>(opart, lpart, obf, o2);

    // wo-GEMM: split-K x4 with atomic f32 accumulate into o2 (zeroed by k_comb)
    gemm_nt<3, false><<<dim3(8, 5, 4), 256, 0, stream>>>(
        obf, woT_l, o2, nullptr, 544, 1024, 1024, 1.f, 544, 0, 1024, 256);
    k_attnln<<<544, 256, 0, stream>>>(o2, lat, olnw + l * 1024, olnb + l * 1024,
                                      ffg1 + l * 1024, latg);
    gemm_nt<0, false><<<dim3(32, 5, 1), 256, 0, stream>>>(
        latg, ffw1T_l, hbuf, nullptr, 544, 4096, 1024, 1.f, 544, 0, 4096, 1024);
    k_geluln<<<544, 256, 0, stream>>>(hbuf, ffg2 + l * 4096, hg);
    // ffw2-GEMM: split-K x8, atomic accumulate into lat (residual already there)
    gemm_nt<3, false><<<dim3(8, 5, 8), 256, 0, stream>>>(
        hg, ffw2T_l, lat, nullptr, 544, 1024, 4096, 1.f, 544, 0, 1024, 512);
  }

  hipMemcpyAsync(d_out, lat, (size_t)out_size * 4, hipMemcpyDeviceToDevice, stream);
}

// Round 8
// 1605.023 us; speedup vs baseline: 3.7877x; 1.0163x over previous
//
#include <hip/hip_runtime.h>

typedef __bf16 bf16x8 __attribute__((ext_vector_type(8)));
typedef float f32x4 __attribute__((ext_vector_type(4)));
typedef unsigned short u16;
typedef unsigned int u32;

typedef __attribute__((address_space(3))) u16 lds_u16;
typedef __attribute__((address_space(1))) const u16 glb_u16;

#define NJC 4

__device__ inline float bf2f(u16 u) { union { u32 i; float f; } x; x.i = (u32)u << 16; return x.f; }
__device__ inline u16 f2bf(float f) {
  union { float f; u32 i; } u; u.f = f;
  u32 r = u.i + 0x7fffu + ((u.i >> 16) & 1u);
  return (u16)(r >> 16);
}

__device__ inline float blk_sum256(float v, float* red) {
#pragma unroll
  for (int o = 32; o > 0; o >>= 1) v += __shfl_xor(v, o);
  __syncthreads();
  if ((threadIdx.x & 63) == 0) red[threadIdx.x >> 6] = v;
  __syncthreads();
  return red[0] + red[1] + red[2] + red[3];
}

// ============ kv-projection GEMM: 256x256 tile, 8 waves (FROZEN, best: 157.6 µs) =====
// 3 schedules x 2 occupancy regimes all land 157-160 µs -> structure wall.
// Cooperative-tail fusion REFUTED (R7): hipLaunchCooperativeKernel does not execute
// under the harness's graph capture -> silent wrong output. Do not retry.
__global__ __launch_bounds__(512, 1) void gemm_kv(const u16* __restrict__ A,
                                                  const u16* __restrict__ BT,
                                                  u16* __restrict__ C,
                                                  const float* __restrict__ bias) {
  extern __shared__ __align__(16) u16 lds[];  // [4 pairs][2 (A,B)][8192 elems]
  const int tid = threadIdx.x, l = tid & 63, w = tid >> 6;
  const int wr = w >> 2, wc = w & 3;
  int bid = blockIdx.x;
  int swz = (bid & 7) * 128 + (bid >> 3);
  int by = swz >> 3, bx = swz & 7;
  const long m0 = (long)by * 256;
  const int n0 = bx * 256;

  long srcA[2], srcB[2];
#pragma unroll
  for (int s = 0; s < 2; s++) {
    int g = s * 512 + tid;
    int p = g >> 3, j = g & 7, jp = j ^ (p & 7);
    int row = (p << 1) | (jp >> 2), cc = jp & 3;
    srcA[s] = (m0 + row) * 1024 + cc * 8;
    srcB[s] = ((long)(n0 + row)) * 1024 + cc * 8;
  }
  const int ldsoff[2] = { (w * 64) * 8, (512 + w * 64) * 8 };

  const int rA = l & 15, cch = l >> 4;
  const int R0a = wr * 128 + rA;
  const int aoff = (R0a >> 1) * 64 + (((((R0a & 1) << 2) | cch) ^ ((R0a >> 1) & 7)) << 3);
  const int R0b = wc * 64 + rA;
  const int boff = (R0b >> 1) * 64 + (((((R0b & 1) << 2) | cch) ^ ((R0b >> 1) & 7)) << 3);

  f32x4 acc[8][4] = {};

  auto stage = [&](int t, int ab) {
    u16* dst = lds + (((t & 3) * 2 + ab) << 13);
    const u16* src = ab == 0 ? A : BT;
    const long* so = ab == 0 ? srcA : srcB;
    int kt = t * 32;
#pragma unroll
    for (int s = 0; s < 2; s++)
      __builtin_amdgcn_global_load_lds((glb_u16*)(src + so[s] + kt),
                                       (lds_u16*)(dst + ldsoff[s]), 16, 0, 0);
  };

  stage(0, 0); stage(0, 1); stage(1, 0); stage(1, 1); stage(2, 0); stage(2, 1);
  asm volatile("s_waitcnt vmcnt(8)" ::: "memory");
  __builtin_amdgcn_s_barrier();

  for (int t = 0; t < 16; ++t) {
    const int s = 2 * t;
    const u16* Ab0 = lds + (((s & 3) * 2 + 0) << 13);
    const u16* Bb0 = lds + (((s & 3) * 2 + 1) << 13);
    const u16* Ab1 = lds + ((((s + 1) & 3) * 2 + 0) << 13);
    const u16* Bb1 = lds + ((((s + 1) & 3) * 2 + 1) << 13);
    bf16x8 af[8], b0, b1;

#pragma unroll
    for (int mf = 0; mf < 8; mf++) af[mf] = *(const bf16x8*)(Ab0 + aoff + mf * 512);
    b0 = *(const bf16x8*)(Bb0 + boff);
    b1 = *(const bf16x8*)(Bb0 + boff + 512);
    if (s + 3 < 32) stage(s + 3, 0);
    __builtin_amdgcn_s_barrier();
    asm volatile("s_waitcnt lgkmcnt(0)" ::: "memory");
    __builtin_amdgcn_sched_barrier(0);
    __builtin_amdgcn_s_setprio(1);
#pragma unroll
    for (int mf = 0; mf < 8; mf++) {
      acc[mf][0] = __builtin_amdgcn_mfma_f32_16x16x32_bf16(af[mf], b0, acc[mf][0], 0, 0, 0);
      acc[mf][1] = __builtin_amdgcn_mfma_f32_16x16x32_bf16(af[mf], b1, acc[mf][1], 0, 0, 0);
    }
    __builtin_amdgcn_s_setprio(0);
    __builtin_amdgcn_s_barrier();

    b0 = *(const bf16x8*)(Bb0 + boff + 1024);
    b1 = *(const bf16x8*)(Bb0 + boff + 1536);
    if (s + 3 < 32) stage(s + 3, 1);
    __builtin_amdgcn_s_barrier();
    asm volatile("s_waitcnt lgkmcnt(0)" ::: "memory");
    __builtin_amdgcn_sched_barrier(0);
    __builtin_amdgcn_s_setprio(1);
#pragma unroll
    for (int mf = 0; mf < 8; mf++) {
      acc[mf][2] = __builtin_amdgcn_mfma_f32_16x16x32_bf16(af[mf], b0, acc[mf][2], 0, 0, 0);
      acc[mf][3] = __builtin_amdgcn_mfma_f32_16x16x32_bf16(af[mf], b1, acc[mf][3], 0, 0, 0);
    }
    __builtin_amdgcn_s_setprio(0);
    if (t < 15) asm volatile("s_waitcnt vmcnt(8)" ::: "memory");
    else        asm volatile("s_waitcnt vmcnt(0)" ::: "memory");
    __builtin_amdgcn_s_barrier();

#pragma unroll
    for (int mf = 0; mf < 8; mf++) af[mf] = *(const bf16x8*)(Ab1 + aoff + mf * 512);
    b0 = *(const bf16x8*)(Bb1 + boff);
    b1 = *(const bf16x8*)(Bb1 + boff + 512);
    if (s + 4 < 32) stage(s + 4, 0);
    __builtin_amdgcn_s_barrier();
    asm volatile("s_waitcnt lgkmcnt(0)" ::: "memory");
    __builtin_amdgcn_sched_barrier(0);
    __builtin_amdgcn_s_setprio(1);
#pragma unroll
    for (int mf = 0; mf < 8; mf++) {
      acc[mf][0] = __builtin_amdgcn_mfma_f32_16x16x32_bf16(af[mf], b0, acc[mf][0], 0, 0, 0);
      acc[mf][1] = __builtin_amdgcn_mfma_f32_16x16x32_bf16(af[mf], b1, acc[mf][1], 0, 0, 0);
    }
    __builtin_amdgcn_s_setprio(0);
    __builtin_amdgcn_s_barrier();

    b0 = *(const bf16x8*)(Bb1 + boff + 1024);
    b1 = *(const bf16x8*)(Bb1 + boff + 1536);
    if (s + 4 < 32) stage(s + 4, 1);
    __builtin_amdgcn_s_barrier();
    asm volatile("s_waitcnt lgkmcnt(0)" ::: "memory");
    __builtin_amdgcn_sched_barrier(0);
    __builtin_amdgcn_s_setprio(1);
#pragma unroll
    for (int mf = 0; mf < 8; mf++) {
      acc[mf][2] = __builtin_amdgcn_mfma_f32_16x16x32_bf16(af[mf], b0, acc[mf][2], 0, 0, 0);
      acc[mf][3] = __builtin_amdgcn_mfma_f32_16x16x32_bf16(af[mf], b1, acc[mf][3], 0, 0, 0);
    }
    __builtin_amdgcn_s_setprio(0);
    if (t < 14)       asm volatile("s_waitcnt vmcnt(8)" ::: "memory");
    else if (t == 14) asm volatile("s_waitcnt vmcnt(4)" ::: "memory");
    __builtin_amdgcn_s_barrier();
  }

  const long batch_off = (m0 >> 12) * ((long)4164 * 2048);
  const int rb0 = (int)(m0 & 4095) + wr * 128 + ((l >> 4) << 2);
#pragma unroll
  for (int mf = 0; mf < 8; mf++) {
#pragma unroll
    for (int nf = 0; nf < 4; nf++) {
      int col = n0 + wc * 64 + nf * 16 + (l & 15);
      float bv = bias[col];
#pragma unroll
      for (int rr = 0; rr < 4; rr++) {
        int rloc = rb0 + mf * 16 + rr;
        C[batch_off + (long)rloc * 2048 + col] = f2bf(acc[mf][nf][rr] + bv);
      }
    }
  }
}

// ---------------- general GEMM (small shapes): C = alpha*A@BT^T (+bias) -------------
// Ring-2 double-buffered staging with raw s_barrier + counted vmcnt.
// MODE 0: f32 store; 1: bf16 store; 2: f32 += (single writer); 3: f32 atomicAdd
template <int MODE, bool BIAS>
__global__ __launch_bounds__(256) void gemm_nt(const u16* __restrict__ A,
                                               const u16* __restrict__ BT,
                                               void* __restrict__ C,
                                               const float* __restrict__ bias,
                                               int M, int N, int K, float alpha,
                                               int RB, long BS, int LDC, int KC) {
  __shared__ __align__(16) u16 As[2][128 * 64];
  __shared__ __align__(16) u16 Bs[2][128 * 64];
  int m0 = blockIdx.y * 128, n0 = blockIdx.x * 128;
  int tid = threadIdx.x;
  int l = tid & 63, w = tid >> 6;
  int wr = w >> 1, wc = w & 1;
  f32x4 acc[4][4] = {};

  const int srow = l >> 3;
  const int scol = (l & 7) * 8;
  const int Mc = M - 1;
  const int k0 = blockIdx.z * KC;
  const int k1 = (k0 + KC < K) ? k0 + KC : K;

  auto stage = [&](int kt, int pb) {
#pragma unroll
    for (int r = 0; r < 4; r++) {
      int rowg = (r * 4 + w) * 8;
      int arow = m0 + rowg + srow; if (arow > Mc) arow = Mc;
      int brow = n0 + rowg + srow;
      const u16* ag = A + (long)arow * K + kt + scol;
      const u16* bg = BT + (long)brow * K + kt + scol;
      __builtin_amdgcn_global_load_lds((glb_u16*)ag, (lds_u16*)(&As[pb][rowg * 64]), 16, 0, 0);
      __builtin_amdgcn_global_load_lds((glb_u16*)bg, (lds_u16*)(&Bs[pb][rowg * 64]), 16, 0, 0);
    }
  };

  stage(k0, 0);
  int it = 0;
  for (int kt = k0; kt < k1; kt += 64, ++it) {
    const int pb = it & 1;
    const bool more = (kt + 64) < k1;
    if (more) stage(kt + 64, pb ^ 1);
    if (more) asm volatile("s_waitcnt vmcnt(8)" ::: "memory");
    else      asm volatile("s_waitcnt vmcnt(0)" ::: "memory");
    __builtin_amdgcn_sched_barrier(0);
    __builtin_amdgcn_s_barrier();
    const u16* Ab = &As[pb][0];
    const u16* Bb = &Bs[pb][0];
#pragma unroll
    for (int kk = 0; kk < 2; kk++) {
      bf16x8 af[4], bfv[4];
#pragma unroll
      for (int mf = 0; mf < 4; mf++)
        af[mf] = *(const bf16x8*)(Ab + (wr * 64 + mf * 16 + (l & 15)) * 64 + kk * 32 + (l >> 4) * 8);
#pragma unroll
      for (int nf = 0; nf < 4; nf++)
        bfv[nf] = *(const bf16x8*)(Bb + (wc * 64 + nf * 16 + (l & 15)) * 64 + kk * 32 + (l >> 4) * 8);
#pragma unroll
      for (int mf = 0; mf < 4; mf++)
#pragma unroll
        for (int nf = 0; nf < 4; nf++)
          acc[mf][nf] = __builtin_amdgcn_mfma_f32_16x16x32_bf16(af[mf], bfv[nf], acc[mf][nf], 0, 0, 0);
    }
    __builtin_amdgcn_sched_barrier(0);
    __builtin_amdgcn_s_barrier();
  }

#pragma unroll
  for (int mf = 0; mf < 4; mf++) {
#pragma unroll
    for (int nf = 0; nf < 4; nf++) {
      int col = n0 + wc * 64 + nf * 16 + (l & 15);
      float bv = 0.f;
      if (BIAS) bv = bias[col];
#pragma unroll
      for (int rr = 0; rr < 4; rr++) {
        int row = m0 + wr * 64 + mf * 16 + (l >> 4) * 4 + rr;
        if (row < M) {
          float v = acc[mf][nf][rr] * alpha + bv;
          long off = (long)(row / RB) * BS + (long)(row % RB) * LDC + col;
          if (MODE == 0) ((float*)C)[off] = v;
          else if (MODE == 1) ((u16*)C)[off] = f2bf(v);
          else if (MODE == 2) ((float*)C)[off] += v;
          else atomicAdd(&((float*)C)[off], v);
        }
      }
    }
  }
}

// ---------------- fused q-proj + kvlat-proj (both read lnlat, M=544, K=1024) --------
__global__ __launch_bounds__(256) void gemm_two(const u16* __restrict__ A,
                                                const u16* __restrict__ BTq,
                                                const u16* __restrict__ BTkv,
                                                u16* __restrict__ Cq,
                                                u16* __restrict__ Ckv) {
  __shared__ __align__(16) u16 As[2][128 * 64];
  __shared__ __align__(16) u16 Bs[2][128 * 64];
  const int K = 1024, M = 544;
  int bxr = blockIdx.x;
  const u16* BT; u16* C; float alpha; int RB; long BS; int LDC; int n0;
  if (bxr < 8) { BT = BTq;  C = Cq;  alpha = 0.125f; RB = 544; BS = 0;                 LDC = 1024; n0 = bxr * 128; }
  else         { BT = BTkv; C = Ckv; alpha = 1.f;    RB = 68;  BS = (long)4164 * 2048; LDC = 2048; n0 = (bxr - 8) * 128; }
  int m0 = blockIdx.y * 128;
  int tid = threadIdx.x;
  int l = tid & 63, w = tid >> 6;
  int wr = w >> 1, wc = w & 1;
  f32x4 acc[4][4] = {};

  const int srow = l >> 3;
  const int scol = (l & 7) * 8;
  const int Mc = M - 1;

  auto stage = [&](int kt, int pb) {
#pragma unroll
    for (int r = 0; r < 4; r++) {
      int rowg = (r * 4 + w) * 8;
      int arow = m0 + rowg + srow; if (arow > Mc) arow = Mc;
      int brow = n0 + rowg + srow;
      const u16* ag = A + (long)arow * K + kt + scol;
      const u16* bg = BT + (long)brow * K + kt + scol;
      __builtin_amdgcn_global_load_lds((glb_u16*)ag, (lds_u16*)(&As[pb][rowg * 64]), 16, 0, 0);
      __builtin_amdgcn_global_load_lds((glb_u16*)bg, (lds_u16*)(&Bs[pb][rowg * 64]), 16, 0, 0);
    }
  };

  stage(0, 0);
  int it = 0;
  for (int kt = 0; kt < K; kt += 64, ++it) {
    const int pb = it & 1;
    const bool more = (kt + 64) < K;
    if (more) stage(kt + 64, pb ^ 1);
    if (more) asm volatile("s_waitcnt vmcnt(8)" ::: "memory");
    else      asm volatile("s_waitcnt vmcnt(0)" ::: "memory");
    __builtin_amdgcn_sched_barrier(0);
    __builtin_amdgcn_s_barrier();
    const u16* Ab = &As[pb][0];
    const u16* Bb = &Bs[pb][0];
#pragma unroll
    for (int kk = 0; kk < 2; kk++) {
      bf16x8 af[4], bfv[4];
#pragma unroll
      for (int mf = 0; mf < 4; mf++)
        af[mf] = *(const bf16x8*)(Ab + (wr * 64 + mf * 16 + (l & 15)) * 64 + kk * 32 + (l >> 4) * 8);
#pragma unroll
      for (int nf = 0; nf < 4; nf++)
        bfv[nf] = *(const bf16x8*)(Bb + (wc * 64 + nf * 16 + (l & 15)) * 64 + kk * 32 + (l >> 4) * 8);
#pragma unroll
      for (int mf = 0; mf < 4; mf++)
#pragma unroll
        for (int nf = 0; nf < 4; nf++)
          acc[mf][nf] = __builtin_amdgcn_mfma_f32_16x16x32_bf16(af[mf], bfv[nf], acc[mf][nf], 0, 0, 0);
    }
    __builtin_amdgcn_sched_barrier(0);
    __builtin_amdgcn_s_barrier();
  }

#pragma unroll
  for (int mf = 0; mf < 4; mf++) {
#pragma unroll
    for (int nf = 0; nf < 4; nf++) {
      int col = n0 + wc * 64 + nf * 16 + (l & 15);
#pragma unroll
      for (int rr = 0; rr < 4; rr++) {
        int row = m0 + wr * 64 + mf * 16 + (l >> 4) * 4 + rr;
        if (row < M) {
          float v = acc[mf][nf][rr] * alpha;
          long off = (long)(row / RB) * BS + (long)(row % RB) * LDC + col;
          C[off] = f2bf(v);
        }
      }
    }
  }
}

// ---------------- transpose + optional row-scale + f32->bf16 (batched over z) -------
__global__ __launch_bounds__(256) void k_transpose(const float* __restrict__ W,
                                                   const float* __restrict__ scale,
                                                   u16* __restrict__ WT, int K, int N,
                                                   long wls, long sls, long tls) {
  __shared__ float tile[32][33];
  int z = blockIdx.z;
  W += (long)z * wls; WT += (long)z * tls;
  if (scale) scale += (long)z * sls;
  int n0 = blockIdx.x * 32, k0 = blockIdx.y * 32;
  int x = threadIdx.x, y = threadIdx.y;
#pragma unroll
  for (int i = 0; i < 4; i++) tile[y + 8 * i][x] = W[(long)(k0 + y + 8 * i) * N + n0 + x];
  __syncthreads();
#pragma unroll
  for (int i = 0; i < 4; i++) {
    int k = k0 + x, n = n0 + y + 8 * i;
    float v = tile[x][y + 8 * i];
    if (scale) v *= scale[k];
    WT[(long)n * K + k] = f2bf(v);
  }
}

__global__ __launch_bounds__(256) void k_transpose2(const float* __restrict__ W,
                                                    const float* __restrict__ scale,
                                                    u16* __restrict__ WTs,
                                                    u16* __restrict__ WTp, int K, int N,
                                                    long wls, long sls, long tls) {
  __shared__ float tile[32][33];
  int z = blockIdx.z;
  W += (long)z * wls; scale += (long)z * sls;
  WTs += (long)z * tls; WTp += (long)z * tls;
  int n0 = blockIdx.x * 32, k0 = blockIdx.y * 32;
  int x = threadIdx.x, y = threadIdx.y;
#pragma unroll
  for (int i = 0; i < 4; i++) tile[y + 8 * i][x] = W[(long)(k0 + y + 8 * i) * N + n0 + x];
  __syncthreads();
#pragma unroll
  for (int i = 0; i < 4; i++) {
    int k = k0 + x, n = n0 + y + 8 * i;
    float v = tile[x][y + 8 * i];
    WTp[(long)n * K + k] = f2bf(v);
    WTs[(long)n * K + k] = f2bf(v * scale[k]);
  }
}

// ---------------- xp_hat = normalize(x + pos_emb) per row, bf16 ---------------------
__global__ __launch_bounds__(256) void k_xphat(const float* __restrict__ x,
                                               const float* __restrict__ pos,
                                               u16* __restrict__ xph) {
  __shared__ float red[4];
  long row = blockIdx.x;
  int n = blockIdx.x & 4095;
  const float* xr = x + row * 1024;
  const float* pr = pos + (long)n * 1024;
  float v[4]; float s = 0.f;
#pragma unroll
  for (int i = 0; i < 4; i++) { int c = threadIdx.x + i * 256; v[i] = xr[c] + pr[c]; s += v[i]; }
  float mean = blk_sum256(s, red) * (1.f / 1024.f);
  float s2 = 0.f;
#pragma unroll
  for (int i = 0; i < 4; i++) { float d = v[i] - mean; s2 += d * d; }
  float rs = rsqrtf(blk_sum256(s2, red) * (1.f / 1024.f) + 1e-5f);
#pragma unroll
  for (int i = 0; i < 4; i++) xph[row * 1024 + threadIdx.x + i * 256] = f2bf((v[i] - mean) * rs);
}

// ---------------- mp: column sums of x over n ---------------------------------------
__global__ __launch_bounds__(256) void k_mp(const float* __restrict__ x, float* __restrict__ macc) {
  int d = blockIdx.x * 256 + threadIdx.x;
  int nc = blockIdx.y, b = blockIdx.z;
  const float* xb = x + (long)b * 4096 * 1024;
  float s = 0.f;
  for (int n = nc * 256; n < nc * 256 + 256; n++) s += xb[(long)n * 1024 + d];
  atomicAdd(&macc[b * 1024 + d], s);
}

__global__ __launch_bounds__(256) void k_mphat(const float* __restrict__ macc,
                                               const float* __restrict__ g,
                                               float* __restrict__ mphat) {
  __shared__ float red[4];
  int b = blockIdx.x;
  float v[4]; float s = 0.f;
#pragma unroll
  for (int i = 0; i < 4; i++) { v[i] = macc[b * 1024 + threadIdx.x + i * 256] * (1.f / 4096.f); s += v[i]; }
  float mean = blk_sum256(s, red) * (1.f / 1024.f);
  float s2 = 0.f;
#pragma unroll
  for (int i = 0; i < 4; i++) { float d = v[i] - mean; s2 += d * d; }
  float rs = rsqrtf(blk_sum256(s2, red) * (1.f / 1024.f) + 1e-5f);
#pragma unroll
  for (int i = 0; i < 4; i++) {
    int c = threadIdx.x + i * 256;
    mphat[b * 1024 + c] = (v[i] - mean) * rs * g[c];
  }
}

__global__ __launch_bounds__(256) void k_mplat(const float* __restrict__ mphat,
                                               const float* __restrict__ w,
                                               const float* __restrict__ bias,
                                               float* __restrict__ lat) {
  int j = blockIdx.x * 256 + threadIdx.x;
  int b = blockIdx.y;
  const float* mh = mphat + b * 1024;
  float s = bias[j];
  for (int k = 0; k < 1024; k++) s += mh[k] * w[(long)k * 4096 + j];
  lat[(long)b * 69632 + (j >> 10) * 1024 + (j & 1023)] = s;
}

__global__ __launch_bounds__(256) void k_latfill(const float* __restrict__ latents,
                                                 float* __restrict__ lat) {
  int idx = blockIdx.x * 256 + threadIdx.x;
  int b = idx >> 16, rest = idx & 65535;
  lat[(long)b * 69632 + 4096 + rest] = latents[rest];
}

// ---------------- lnlat = LN(lat)*w+b  -> bf16 -------------------------------------
__global__ __launch_bounds__(256) void k_lnrow(const float* __restrict__ in,
                                               const float* __restrict__ w,
                                               const float* __restrict__ bb,
                                               u16* __restrict__ out) {
  __shared__ float red[4];
  long row = blockIdx.x;
  const float* xr = in + row * 1024;
  float v[4]; float s = 0.f;
#pragma unroll
  for (int i = 0; i < 4; i++) { v[i] = xr[threadIdx.x + i * 256]; s += v[i]; }
  float mean = blk_sum256(s, red) * (1.f / 1024.f);
  float s2 = 0.f;
#pragma unroll
  for (int i = 0; i < 4; i++) { float d = v[i] - mean; s2 += d * d; }
  float rs = rsqrtf(blk_sum256(s2, red) * (1.f / 1024.f) + 1e-5f);
#pragma unroll
  for (int i = 0; i < 4; i++) {
    int c = threadIdx.x + i * 256;
    out[row * 1024 + c] = f2bf((v[i] - mean) * rs * w[c] + bb[c]);
  }
}

// ---------------- bias fold (batched over z = layer) --------------------------------
__global__ __launch_bounds__(256) void k_bias1(const float* __restrict__ wkv,
                                               const float* __restrict__ lnxb,
                                               float* __restrict__ bxp,
                                               long wls, long bls, long pls) {
  int z = blockIdx.z;
  wkv += (long)z * wls; lnxb += (long)z * bls; bxp += (long)z * pls;
  int n = blockIdx.x * 256 + threadIdx.x;
  int kc = blockIdx.y;
  float s = 0.f;
  for (int k = kc * 64; k < kc * 64 + 64; k++) s += lnxb[k] * wkv[(long)k * 2048 + n];
  bxp[kc * 2048 + n] = s;
}
__global__ __launch_bounds__(256) void k_bias2(const float* __restrict__ bxp,
                                               float* __restrict__ bx,
                                               long pls, long xls) {
  int z = blockIdx.y;
  bxp += (long)z * pls; bx += (long)z * xls;
  int n = blockIdx.x * 256 + threadIdx.x;
  float s = 0.f;
#pragma unroll
  for (int kc = 0; kc < 16; kc++) s += bxp[kc * 2048 + n];
  bx[n] = s;
}

// ---------------- MFMA flash attention, T14 software-pipelined ----------------------
__global__ __launch_bounds__(256) void k_flash(const u16* __restrict__ q,
                                               const u16* __restrict__ kv,
                                               float* __restrict__ opart,
                                               float* __restrict__ lpart) {
  int c = blockIdx.x, h = blockIdx.y, b = blockIdx.z;
  int tid = threadIdx.x, l = tid & 63, w = tid >> 6;

  __shared__ __align__(16) char smem_raw[46080];
  u16 (*Vt)[64][40] = reinterpret_cast<u16(*)[64][40]>(smem_raw);
  u16 (*Pl)[80][40] = reinterpret_cast<u16(*)[80][40]>(smem_raw + 20480);
  float (*O_s)[64] = reinterpret_cast<float(*)[64]>(smem_raw);
  float* l_s = reinterpret_cast<float*>(smem_raw + 20480);

  const int JCH = 1041;
  const int jstart = c * JCH;
  const int jend = (c == NJC - 1) ? 4164 : jstart + JCH;
  const long kvbase = (long)b * 4164 * 2048;
  const u16* Kp = kv + kvbase + h * 64;
  const u16* Vp = kv + kvbase + 1024 + h * 64;

  bf16x8 qf[5][2];
#pragma unroll
  for (int it = 0; it < 5; it++) {
    int qi = it * 16 + (l & 15); if (qi > 67) qi = 67;
    const u16* qrow = q + ((long)(b * 68 + qi) * 1024 + h * 64 + (l >> 4) * 8);
    qf[it][0] = *(const bf16x8*)(qrow);
    qf[it][1] = *(const bf16x8*)(qrow + 32);
  }

  f32x4 Of[5][4] = {};
  float lac[5] = {0.f, 0.f, 0.f, 0.f, 0.f};

  auto loadV = [&](int j0, uint4 vv[4]) {
#pragma unroll
    for (int t = 0; t < 4; t++) {
      int vj = j0 + (l & 31);
      int vjc = vj < 4163 ? vj : 4163;
      int vd = (l >> 5) * 8 + t * 16;
      vv[t] = *(const uint4*)(Vp + (long)vjc * 2048 + vd);
    }
  };
  auto loadK = [&](int j0, bf16x8& a00, bf16x8& a01, bf16x8& a10, bf16x8& a11) {
    const u16* kr0 = Kp + (long)(j0 + (l & 15)) * 2048 + (l >> 4) * 8;
    a00 = *(const bf16x8*)(kr0);
    a01 = *(const bf16x8*)(kr0 + 32);
    const u16* kr1 = Kp + (long)(j0 + 16 + (l & 15)) * 2048 + (l >> 4) * 8;
    a10 = *(const bf16x8*)(kr1);
    a11 = *(const bf16x8*)(kr1 + 32);
  };

  const int jbeg = jstart + w * 32;
  uint4 vr[4];
  bf16x8 k0a, k0b, k1a, k1b;
  if (jbeg < jend) { loadV(jbeg, vr); loadK(jbeg, k0a, k0b, k1a, k1b); }

  for (int j0 = jbeg; j0 < jend; j0 += 4 * 32) {
#pragma unroll
    for (int t = 0; t < 4; t++) {
      int vd = (l >> 5) * 8 + t * 16;
      union { uint4 q4; u16 s[8]; } uu; uu.q4 = vr[t];
#pragma unroll
      for (int e = 0; e < 8; e++) Vt[w][vd + e][l & 31] = uu.s[e];
    }
    f32x4 sf[2][5];
#pragma unroll
    for (int it = 0; it < 5; it++) {
      f32x4 d0 = {};
      d0 = __builtin_amdgcn_mfma_f32_16x16x32_bf16(k0a, qf[it][0], d0, 0, 0, 0);
      d0 = __builtin_amdgcn_mfma_f32_16x16x32_bf16(k0b, qf[it][1], d0, 0, 0, 0);
      sf[0][it] = d0;
      f32x4 d1 = {};
      d1 = __builtin_amdgcn_mfma_f32_16x16x32_bf16(k1a, qf[it][0], d1, 0, 0, 0);
      d1 = __builtin_amdgcn_mfma_f32_16x16x32_bf16(k1b, qf[it][1], d1, 0, 0, 0);
      sf[1][it] = d1;
    }
    int jn = j0 + 4 * 32;
    bool more = jn < jend;
    uint4 vr2[4];
    bf16x8 n0a, n0b, n1a, n1b;
    if (more) { loadV(jn, vr2); loadK(jn, n0a, n0b, n1a, n1b); }
#pragma unroll
    for (int jt = 0; jt < 2; jt++) {
      int jb = j0 + jt * 16 + (l >> 4) * 4;
#pragma unroll
      for (int it = 0; it < 5; it++) {
        u16 pk[4];
#pragma unroll
        for (int r = 0; r < 4; r++) {
          float p = (jb + r < jend) ? __expf(sf[jt][it][r]) : 0.f;
          lac[it] += p;
          pk[r] = f2bf(p);
        }
        *(uint2*)(&Pl[w][it * 16 + (l & 15)][jt * 16 + (l >> 4) * 4]) = *(const uint2*)pk;
      }
    }
#pragma unroll
    for (int it = 0; it < 5; it++) {
      bf16x8 pa = *(const bf16x8*)(&Pl[w][it * 16 + (l & 15)][(l >> 4) * 8]);
#pragma unroll
      for (int dt = 0; dt < 4; dt++) {
        bf16x8 vb = *(const bf16x8*)(&Vt[w][dt * 16 + (l & 15)][(l >> 4) * 8]);
        Of[it][dt] = __builtin_amdgcn_mfma_f32_16x16x32_bf16(pa, vb, Of[it][dt], 0, 0, 0);
      }
    }
    if (more) {
      vr[0] = vr2[0]; vr[1] = vr2[1]; vr[2] = vr2[2]; vr[3] = vr2[3];
      k0a = n0a; k0b = n0b; k1a = n1a; k1b = n1b;
    }
  }

  __syncthreads();
  for (int u = tid; u < 80 * 64; u += 256) ((float*)O_s)[u] = 0.f;
  if (tid < 80) l_s[tid] = 0.f;
  __syncthreads();
#pragma unroll
  for (int it = 0; it < 5; it++) {
    float v = lac[it];
    v += __shfl_xor(v, 16);
    v += __shfl_xor(v, 32);
    if (l < 16) atomicAdd(&l_s[it * 16 + l], v);
#pragma unroll
    for (int dt = 0; dt < 4; dt++) {
#pragma unroll
      for (int r = 0; r < 4; r++) {
        int i = it * 16 + (l >> 4) * 4 + r;
        int d = dt * 16 + (l & 15);
        atomicAdd(&O_s[i][d], Of[it][dt][r]);
      }
    }
  }
  __syncthreads();
  long base = (long)((b * 16 + h) * NJC + c);
  for (int u = tid; u < 68 * 64; u += 256)
    opart[base * 68 * 64 + u] = O_s[u >> 6][u & 63];
  if (tid < 68) lpart[base * 68 + tid] = l_s[tid];
}

// ---------------- combine partials -> obf bf16; also zero o2 for the wo split-K ----
__global__ __launch_bounds__(256) void k_comb(const float* __restrict__ opart,
                                              const float* __restrict__ lpart,
                                              u16* __restrict__ obf,
                                              float* __restrict__ o2z) {
  int r = blockIdx.x;
  int b = r / 68, i = r % 68;
#pragma unroll
  for (int it = 0; it < 4; it++) {
    int col = threadIdx.x + it * 256;
    int h = col >> 6, d = col & 63;
    long bh = (long)(b * 16 + h) * NJC;
    float os = 0.f, ls = 0.f;
    for (int cc = 0; cc < NJC; cc++) {
      os += opart[(bh + cc) * 68 * 64 + (long)i * 64 + d];
      ls += lpart[(bh + cc) * 68 + i];
    }
    obf[(long)r * 1024 + col] = f2bf(os / ls);
    o2z[(long)r * 1024 + col] = 0.f;
  }
}

// ---------------- o-path: lat += LN(o2)*w+b ; latg = LN_g(lat_new)*g ----------------
// Also zeroes this row of hbuf so the following ffw1 GEMM can run split-K atomic.
__global__ __launch_bounds__(256) void k_attnln(const float* __restrict__ o2,
                                                float* __restrict__ lat,
                                                const float* __restrict__ w,
                                                const float* __restrict__ bb,
                                                const float* __restrict__ g,
                                                u16* __restrict__ latg,
                                                float* __restrict__ hbufz) {
  __shared__ float red[4];
  long row = blockIdx.x;
  const float* xr = o2 + row * 1024;
  float* lr = lat + row * 1024;
  float v[4]; float s = 0.f;
#pragma unroll
  for (int i = 0; i < 4; i++) { v[i] = xr[threadIdx.x + i * 256]; s += v[i]; }
  float mean = blk_sum256(s, red) * (1.f / 1024.f);
  float s2 = 0.f;
#pragma unroll
  for (int i = 0; i < 4; i++) { float d = v[i] - mean; s2 += d * d; }
  float rs = rsqrtf(blk_sum256(s2, red) * (1.f / 1024.f) + 1e-5f);
  float lv[4]; float sl = 0.f;
#pragma unroll
  for (int i = 0; i < 4; i++) {
    int c = threadIdx.x + i * 256;
    float t = (v[i] - mean) * rs * w[c] + bb[c];
    lv[i] = lr[c] + t;
    lr[c] = lv[i];
    sl += lv[i];
  }
  float mean2 = blk_sum256(sl, red) * (1.f / 1024.f);
  float s22 = 0.f;
#pragma unroll
  for (int i = 0; i < 4; i++) { float d = lv[i] - mean2; s22 += d * d; }
  float rs2 = rsqrtf(blk_sum256(s22, red) * (1.f / 1024.f) + 1e-5f);
#pragma unroll
  for (int i = 0; i < 4; i++) {
    int c = threadIdx.x + i * 256;
    latg[row * 1024 + c] = f2bf((lv[i] - mean2) * rs2 * g[c]);
  }
#pragma unroll
  for (int i = 0; i < 16; i++) hbufz[row * 4096 + threadIdx.x + i * 256] = 0.f;
}

// ---------------- FF mid: hg = LN_g(gelu(h))*g2 -------------------------------------
__global__ __launch_bounds__(256) void k_geluln(const float* __restrict__ hin,
                                                const float* __restrict__ g,
                                                u16* __restrict__ out) {
  __shared__ float red[4];
  long row = blockIdx.x;
  const float* xr = hin + row * 4096;
  float v[16]; float s = 0.f;
#pragma unroll
  for (int i = 0; i < 16; i++) {
    int c = threadIdx.x + i * 256;
    float u = xr[c];
    u = 0.5f * u * (1.f + erff(u * 0.70710678118f));
    v[i] = u; s += u;
  }
  float mean = blk_sum256(s, red) * (1.f / 4096.f);
  float s2 = 0.f;
#pragma unroll
  for (int i = 0; i < 16; i++) { float d = v[i] - mean; s2 += d * d; }
  float rs = rsqrtf(blk_sum256(s2, red) * (1.f / 4096.f) + 1e-5f);
#pragma unroll
  for (int i = 0; i < 16; i++) {
    int c = threadIdx.x + i * 256;
    out[row * 4096 + c] = f2bf((v[i] - mean) * rs * g[c]);
  }
}

extern "C" void kernel_launch(void* const* d_in, const int* in_sizes, int n_in,
                              void* d_out, int out_size, void* d_ws, size_t ws_size,
                              hipStream_t stream) {
  const float* x    = (const float*)d_in[0];
  const float* pos  = (const float*)d_in[1];
  const float* lats = (const float*)d_in[2];
  const float* mplng= (const float*)d_in[3];
  const float* mpw  = (const float*)d_in[4];
  const float* mpb  = (const float*)d_in[5];
  const float* lnxw = (const float*)d_in[6];
  const float* lnxb = (const float*)d_in[7];
  const float* lnlw = (const float*)d_in[8];
  const float* lnlb = (const float*)d_in[9];
  const float* wq   = (const float*)d_in[10];
  const float* wkv  = (const float*)d_in[11];
  const float* wo   = (const float*)d_in[12];
  const float* olnw = (const float*)d_in[13];
  const float* olnb = (const float*)d_in[14];
  const float* ffg1 = (const float*)d_in[15];
  const float* ffw1 = (const float*)d_in[16];
  const float* ffg2 = (const float*)d_in[17];
  const float* ffw2 = (const float*)d_in[18];

  char* ws = (char*)d_ws;
  size_t off = 0;
  auto take = [&](size_t n) -> char* {
    off = (off + 255) & ~(size_t)255;
    char* p = ws + off; off += n; return p;
  };
  float* mp_acc = (float*)take(8 * 1024 * 4);
  float* mp_hat = (float*)take(8 * 1024 * 4);
  u16*   xp_hat = (u16*)take((size_t)8 * 4096 * 1024 * 2);
  float* lat    = (float*)take((size_t)8 * 68 * 1024 * 4);
  u16*   lnlat  = (u16*)take((size_t)544 * 1024 * 2);
  u16*   qb     = (u16*)take((size_t)544 * 1024 * 2);
  u16*   kvb    = (u16*)take(((size_t)8 * 4164 + 64) * 2048 * 2);
  float* opart  = (float*)take((size_t)128 * NJC * 68 * 64 * 4);
  float* lpart  = (float*)take((size_t)128 * NJC * 68 * 4);
  u16*   obf    = (u16*)take((size_t)544 * 1024 * 2);
  float* o2     = (float*)take((size_t)544 * 1024 * 4);
  u16*   latg   = (u16*)take((size_t)544 * 1024 * 2);
  float* hbuf   = (float*)take((size_t)544 * 4096 * 4);
  u16*   hg     = (u16*)take((size_t)544 * 4096 * 2);

  // weight buffers: try 4-layer-resident (hoisted prep); fall back to per-layer slots
  size_t fixed_off = off;
  u16 *wqT, *wkvxT, *wkvlT, *woT, *ffw1T, *ffw2T;
  float *bx, *bxp;
  auto alloc_w = [&](size_t rep) {
    wqT   = (u16*)take(rep * (size_t)1024 * 1024 * 2);
    wkvxT = (u16*)take(rep * (size_t)2048 * 1024 * 2);
    wkvlT = (u16*)take(rep * (size_t)2048 * 1024 * 2);
    woT   = (u16*)take(rep * (size_t)1024 * 1024 * 2);
    ffw1T = (u16*)take(rep * (size_t)4096 * 1024 * 2);
    ffw2T = (u16*)take(rep * (size_t)4096 * 1024 * 2);
    bx    = (float*)take(rep * 2048 * 4);
    bxp   = (float*)take(rep * 16 * 2048 * 4);
  };
  alloc_w(4);
  bool hoist = off <= ws_size;
  if (!hoist) { off = fixed_off; alloc_w(1); }

  const long KV_BS = (long)4164 * 2048;

  // ---- precompute ----
  hipMemsetAsync(mp_acc, 0, 8 * 1024 * 4, stream);
  k_xphat<<<32768, 256, 0, stream>>>(x, pos, xp_hat);
  k_mp<<<dim3(4, 16, 8), 256, 0, stream>>>(x, mp_acc);
  k_mphat<<<8, 256, 0, stream>>>(mp_acc, mplng, mp_hat);
  k_mplat<<<dim3(16, 8), 256, 0, stream>>>(mp_hat, mpw, mpb, lat);
  k_latfill<<<2048, 256, 0, stream>>>(lats, lat);

  if (hoist) {
    k_transpose<<<dim3(32, 32, 4), dim3(32, 8), 0, stream>>>(
        wq, nullptr, wqT, 1024, 1024, 1048576, 0, 1048576);
    k_transpose2<<<dim3(64, 32, 4), dim3(32, 8), 0, stream>>>(
        wkv, lnxw, wkvxT, wkvlT, 1024, 2048, 2097152, 1024, 2097152);
    k_transpose<<<dim3(32, 32, 4), dim3(32, 8), 0, stream>>>(
        wo, nullptr, woT, 1024, 1024, 1048576, 0, 1048576);
    k_transpose<<<dim3(128, 32, 4), dim3(32, 8), 0, stream>>>(
        ffw1, nullptr, ffw1T, 1024, 4096, 4194304, 0, 4194304);
    k_transpose<<<dim3(32, 128, 4), dim3(32, 8), 0, stream>>>(
        ffw2, nullptr, ffw2T, 4096, 1024, 4194304, 0, 4194304);
    k_bias1<<<dim3(8, 16, 4), 256, 0, stream>>>(wkv, lnxb, bxp, 2097152, 1024, 32768);
    k_bias2<<<dim3(8, 4), 256, 0, stream>>>(bxp, bx, 32768, 2048);
  }

  for (int l = 0; l < 4; l++) {
    const float* wq_l  = wq  + (size_t)l * 1024 * 1024;
    const float* wkv_l = wkv + (size_t)l * 1024 * 2048;
    const float* wo_l  = wo  + (size_t)l * 1024 * 1024;
    const float* w1_l  = ffw1 + (size_t)l * 1024 * 4096;
    const float* w2_l  = ffw2 + (size_t)l * 4096 * 1024;

    if (!hoist) {
      k_transpose<<<dim3(32, 32, 1), dim3(32, 8), 0, stream>>>(
          wq_l, nullptr, wqT, 1024, 1024, 0, 0, 0);
      k_transpose2<<<dim3(64, 32, 1), dim3(32, 8), 0, stream>>>(
          wkv_l, lnxw + l * 1024, wkvxT, wkvlT, 1024, 2048, 0, 0, 0);
      k_transpose<<<dim3(32, 32, 1), dim3(32, 8), 0, stream>>>(
          wo_l, nullptr, woT, 1024, 1024, 0, 0, 0);
      k_transpose<<<dim3(128, 32, 1), dim3(32, 8), 0, stream>>>(
          w1_l, nullptr, ffw1T, 1024, 4096, 0, 0, 0);
      k_transpose<<<dim3(32, 128, 1), dim3(32, 8), 0, stream>>>(
          w2_l, nullptr, ffw2T, 4096, 1024, 0, 0, 0);
      k_bias1<<<dim3(8, 16, 1), 256, 0, stream>>>(wkv_l, lnxb + l * 1024, bxp, 0, 0, 0);
      k_bias2<<<dim3(8, 1), 256, 0, stream>>>(bxp, bx, 0, 0);
    }
    const u16* wqT_l   = wqT   + (hoist ? (size_t)l * 1048576 : 0);
    const u16* wkvxT_l = wkvxT + (hoist ? (size_t)l * 2097152 : 0);
    const u16* wkvlT_l = wkvlT + (hoist ? (size_t)l * 2097152 : 0);
    const u16* woT_l   = woT   + (hoist ? (size_t)l * 1048576 : 0);
    const u16* ffw1T_l = ffw1T + (hoist ? (size_t)l * 4194304 : 0);
    const u16* ffw2T_l = ffw2T + (hoist ? (size_t)l * 4194304 : 0);
    const float* bx_l  = bx    + (hoist ? (size_t)l * 2048 : 0);

    k_lnrow<<<544, 256, 0, stream>>>(lat, lnlw + l * 1024, lnlb + l * 1024, lnlat);

    gemm_kv<<<1024, 512, 131072, stream>>>(xp_hat, wkvxT_l, kvb, bx_l);
    gemm_two<<<dim3(24, 5), 256, 0, stream>>>(lnlat, wqT_l, wkvlT_l, qb, kvb + (size_t)4096 * 2048);

    k_flash<<<dim3(NJC, 16, 8), 256, 0, stream>>>(qb, kvb, opart, lpart);
    k_comb<<<544, 256, 0, stream>>>(opart, lpart, obf, o2);

    // wo-GEMM: split-K x4 with atomic f32 accumulate into o2 (zeroed by k_comb)
    gemm_nt<3, false><<<dim3(8, 5, 4), 256, 0, stream>>>(
        obf, woT_l, o2, nullptr, 544, 1024, 1024, 1.f, 544, 0, 1024, 256);
    k_attnln<<<544, 256, 0, stream>>>(o2, lat, olnw + l * 1024, olnb + l * 1024,
                                      ffg1 + l * 1024, latg, hbuf);
    // ffw1-GEMM: split-K x2, atomic accumulate into hbuf (zeroed by k_attnln)
    gemm_nt<3, false><<<dim3(32, 5, 2), 256, 0, stream>>>(
        latg, ffw1T_l, hbuf, nullptr, 544, 4096, 1024, 1.f, 544, 0, 4096, 512);
    k_geluln<<<544, 256, 0, stream>>>(hbuf, ffg2 + l * 4096, hg);
    // ffw2-GEMM: split-K x8, atomic accumulate into lat (residual already there)
    gemm_nt<3, false><<<dim3(8, 5, 8), 256, 0, stream>>>(
        hg, ffw2T_l, lat, nullptr, 544, 1024, 4096, 1.f, 544, 0, 1024, 512);
  }

  hipMemcpyAsync(d_out, lat, (size_t)out_size * 4, hipMemcpyDeviceToDevice, stream);
}